// Round 1
// baseline (874.817 us; speedup 1.0000x reference)
//
#include <hip/hip_runtime.h>
#include <math.h>

#define T_SEQ  2048
#define D_MODEL 512
#define NH     8
#define DK     64
#define NKB    (T_SEQ / 64)   // 32 key blocks

// workspace layout in floats
#define Q_OFF   0
#define K_OFF   2097152              // B*H*T*DK
#define V_OFF   (2 * 2097152)
#define ATT_OFF (3 * 2097152)        // [B, T, H*DK] unnormalized
#define M_OFF   (4 * 2097152)        // [B*H, T]
#define L_OFF   (M_OFF + 32768)
#define SC_OFF  (L_OFF + 32768)

// ---------------------------------------------------------------------------
// Kernel 1: QKV projections.  q[b,h,t,k] = sum_d in[b,t,d] * W[h,d,k]
// grid (T/64, B*H, 3), block 256.  64x64 output tile, 4x4 microtile.
// q additionally scaled by 1/sqrt(dk) = 0.125.
// ---------------------------------------------------------------------------
__global__ __launch_bounds__(256) void proj_qkv(
    const float* __restrict__ query, const float* __restrict__ value,
    const float* __restrict__ Wq, const float* __restrict__ Wk,
    const float* __restrict__ Wv, float* __restrict__ ws)
{
    const int which = blockIdx.z;            // 0=q 1=k 2=v
    const int bh = blockIdx.y;
    const int b = bh / NH, h = bh % NH;
    const int row0 = blockIdx.x * 64;

    const float* A = (which == 0 ? query : value) + (size_t)b * T_SEQ * D_MODEL;
    const float* W = (which == 0 ? Wq : (which == 1 ? Wk : Wv)) + (size_t)h * D_MODEL * DK;
    float* O = ws + (which == 0 ? Q_OFF : (which == 1 ? K_OFF : V_OFF))
                  + ((size_t)bh * T_SEQ + row0) * DK;
    const float outscale = (which == 0) ? 0.125f : 1.0f;

    __shared__ float As[64][17];
    __shared__ float Ws[16][64];

    const int tid = threadIdx.x;
    const int tr0 = (tid >> 4) * 4;
    const int tc0 = (tid & 15) * 4;

    float acc[4][4] = {};

    for (int d0 = 0; d0 < D_MODEL; d0 += 16) {
        {
            int r = tid >> 2, c = (tid & 3) * 4;
            float4 a4 = *(const float4*)&A[(size_t)(row0 + r) * D_MODEL + d0 + c];
            As[r][c + 0] = a4.x; As[r][c + 1] = a4.y;
            As[r][c + 2] = a4.z; As[r][c + 3] = a4.w;
        }
        {
            int wr = tid >> 4, wc = (tid & 15) * 4;
            *(float4*)&Ws[wr][wc] = *(const float4*)&W[(size_t)(d0 + wr) * DK + wc];
        }
        __syncthreads();
#pragma unroll
        for (int kk = 0; kk < 16; ++kk) {
            float a[4];
#pragma unroll
            for (int i = 0; i < 4; ++i) a[i] = As[tr0 + i][kk];
            float4 w4 = *(const float4*)&Ws[kk][tc0];
            float w[4] = {w4.x, w4.y, w4.z, w4.w};
#pragma unroll
            for (int i = 0; i < 4; ++i)
#pragma unroll
                for (int j = 0; j < 4; ++j)
                    acc[i][j] = fmaf(a[i], w[j], acc[i][j]);
        }
        __syncthreads();
    }
#pragma unroll
    for (int i = 0; i < 4; ++i) {
        float4 o4 = make_float4(acc[i][0] * outscale, acc[i][1] * outscale,
                                acc[i][2] * outscale, acc[i][3] * outscale);
        *(float4*)&O[(size_t)(tr0 + i) * DK + tc0] = o4;
    }
}

// ---------------------------------------------------------------------------
// Kernel 2: flash-style attention, unnormalized output + per-row (m, l).
// grid (T/64, B*H), block 256.  Per-thread 4x4 microtiles of the 64x64 S tile.
// Masked key-blocks are skipped entirely.
// ---------------------------------------------------------------------------
__global__ __launch_bounds__(256) void attn_fwd(
    const float* __restrict__ ws_in, const int* __restrict__ ls_ptr,
    float* __restrict__ ws_out)
{
    const int bh = blockIdx.y;
    const int b = bh / NH, h = bh % NH;
    const int mtype = h >> 1;                 // 0=global 1=local 2=fwd 3=bwd
    const int row0 = blockIdx.x * 64;
    const int ls = *ls_ptr;

    const float* Q = ws_in + Q_OFF + ((size_t)bh * T_SEQ + row0) * DK;
    const float* K = ws_in + K_OFF + (size_t)bh * T_SEQ * DK;
    const float* V = ws_in + V_OFF + (size_t)bh * T_SEQ * DK;
    float* attU = ws_out + ATT_OFF;
    float* mrow = ws_out + M_OFF;
    float* lrow = ws_out + L_OFF;

    __shared__ float Qs[64][68];
    __shared__ float Ks[64][68];
    __shared__ float Vs[64][68];
    __shared__ float Ps[64][68];

    const int tid = threadIdx.x;
    const int rg = tid >> 4;          // 0..15
    const int cg = tid & 15;          // 0..15
    const int r0 = rg * 4, c0 = cg * 4;

    // load Q tile (scaled already by 0.125 in proj)
    for (int it = 0; it < 4; ++it) {
        int f = tid + 256 * it;       // float4 index over 64x16
        int r = f >> 4, c = (f & 15) * 4;
        *(float4*)&Qs[r][c] = *(const float4*)&Q[(size_t)r * DK + c];
    }

    float m_i[4], l_i[4], O_acc[4][4];
#pragma unroll
    for (int i = 0; i < 4; ++i) {
        m_i[i] = -INFINITY; l_i[i] = 0.f;
#pragma unroll
        for (int j = 0; j < 4; ++j) O_acc[i][j] = 0.f;
    }

    int kb0 = 0, kb1 = NKB - 1;
    if (mtype == 1) {
        int lo = row0 - ls; if (lo < 0) lo = 0;
        int hi = row0 + 63 + ls; if (hi > T_SEQ - 1) hi = T_SEQ - 1;
        kb0 = lo >> 6; kb1 = hi >> 6;
    } else if (mtype == 2) {
        kb0 = row0 >> 6;
    } else if (mtype == 3) {
        kb1 = (row0 + 63) >> 6;
    }

    for (int kb = kb0; kb <= kb1; ++kb) {
        __syncthreads();   // previous PV done before overwriting Ks/Vs
        for (int it = 0; it < 4; ++it) {
            int f = tid + 256 * it;
            int r = f >> 4, c = (f & 15) * 4;
            *(float4*)&Ks[r][c] = *(const float4*)&K[(size_t)(kb * 64 + r) * DK + c];
            *(float4*)&Vs[r][c] = *(const float4*)&V[(size_t)(kb * 64 + r) * DK + c];
        }
        __syncthreads();

        // S = Q K^T (Q pre-scaled)
        float s[4][4] = {};
#pragma unroll
        for (int d = 0; d < DK; d += 4) {
            float4 qv[4], kv[4];
#pragma unroll
            for (int i = 0; i < 4; ++i) qv[i] = *(const float4*)&Qs[r0 + i][d];
#pragma unroll
            for (int j = 0; j < 4; ++j) kv[j] = *(const float4*)&Ks[c0 + j][d];
#pragma unroll
            for (int i = 0; i < 4; ++i)
#pragma unroll
                for (int j = 0; j < 4; ++j) {
                    s[i][j] = fmaf(qv[i].x, kv[j].x, s[i][j]);
                    s[i][j] = fmaf(qv[i].y, kv[j].y, s[i][j]);
                    s[i][j] = fmaf(qv[i].z, kv[j].z, s[i][j]);
                    s[i][j] = fmaf(qv[i].w, kv[j].w, s[i][j]);
                }
        }

        // mask
        const int ibase = row0 + r0, jbase = kb * 64 + c0;
#pragma unroll
        for (int i = 0; i < 4; ++i)
#pragma unroll
            for (int j = 0; j < 4; ++j) {
                int ii = ibase + i, jj = jbase + j;
                bool keep;
                if (mtype == 0) keep = true;
                else if (mtype == 1) keep = (ii - jj <= ls) && (jj - ii <= ls);
                else if (mtype == 2) keep = (jj >= ii);
                else keep = (jj <= ii);
                if (!keep) s[i][j] = -INFINITY;
            }

        // online softmax update, per row (16 lanes per row)
#pragma unroll
        for (int i = 0; i < 4; ++i) {
            float v = fmaxf(fmaxf(s[i][0], s[i][1]), fmaxf(s[i][2], s[i][3]));
#pragma unroll
            for (int off = 1; off < 16; off <<= 1)
                v = fmaxf(v, __shfl_xor(v, off, 16));
            float mn = fmaxf(m_i[i], v);
            float factor, p[4], psum;
            if (mn == -INFINITY) {
                factor = 1.f; p[0] = p[1] = p[2] = p[3] = 0.f; psum = 0.f;
            } else {
                factor = expf(m_i[i] - mn);   // m_i=-inf -> 0
#pragma unroll
                for (int j = 0; j < 4; ++j) p[j] = expf(s[i][j] - mn);
                psum = (p[0] + p[1]) + (p[2] + p[3]);
                m_i[i] = mn;
            }
#pragma unroll
            for (int off = 1; off < 16; off <<= 1)
                psum += __shfl_xor(psum, off, 16);
            l_i[i] = l_i[i] * factor + psum;
#pragma unroll
            for (int j = 0; j < 4; ++j) O_acc[i][j] *= factor;
#pragma unroll
            for (int j = 0; j < 4; ++j) Ps[r0 + i][c0 + j] = p[j];
        }
        __syncthreads();

        // O += P V
#pragma unroll
        for (int c = 0; c < 64; c += 4) {
            float4 pp[4], vv[4];
#pragma unroll
            for (int i = 0; i < 4; ++i) pp[i] = *(const float4*)&Ps[r0 + i][c];
#pragma unroll
            for (int cc = 0; cc < 4; ++cc) vv[cc] = *(const float4*)&Vs[c + cc][c0];
#pragma unroll
            for (int i = 0; i < 4; ++i) {
                float pc[4] = {pp[i].x, pp[i].y, pp[i].z, pp[i].w};
#pragma unroll
                for (int cc = 0; cc < 4; ++cc) {
                    O_acc[i][0] = fmaf(pc[cc], vv[cc].x, O_acc[i][0]);
                    O_acc[i][1] = fmaf(pc[cc], vv[cc].y, O_acc[i][1]);
                    O_acc[i][2] = fmaf(pc[cc], vv[cc].z, O_acc[i][2]);
                    O_acc[i][3] = fmaf(pc[cc], vv[cc].w, O_acc[i][3]);
                }
            }
        }
    }

    // write unnormalized O to attU[b, t, h*64 + k], and (m,l)
#pragma unroll
    for (int i = 0; i < 4; ++i) {
        int t = row0 + r0 + i;
        float4 o4 = make_float4(O_acc[i][0], O_acc[i][1], O_acc[i][2], O_acc[i][3]);
        *(float4*)&attU[((size_t)b * T_SEQ + t) * (NH * DK) + h * DK + c0] = o4;
    }
    if (cg == 0) {
#pragma unroll
        for (int i = 0; i < 4; ++i) {
            int t = row0 + r0 + i;
            mrow[(size_t)bh * T_SEQ + t] = m_i[i];
            lrow[(size_t)bh * T_SEQ + t] = l_i[i];
        }
    }
}

// ---------------------------------------------------------------------------
// Kernel 3: per-(b,h) global reduce of (m,l) -> scale[t] = exp(m_t - M)/Z
// grid (B*H), block 256.
// ---------------------------------------------------------------------------
__global__ __launch_bounds__(256) void softmax_stats(float* __restrict__ ws)
{
    const int bh = blockIdx.x;
    const float* m = ws + M_OFF + (size_t)bh * T_SEQ;
    const float* l = ws + L_OFF + (size_t)bh * T_SEQ;
    float* sc = ws + SC_OFF + (size_t)bh * T_SEQ;

    __shared__ float red[256];
    const int tid = threadIdx.x;

    float mymax = -INFINITY;
    for (int t = tid; t < T_SEQ; t += 256) mymax = fmaxf(mymax, m[t]);
    red[tid] = mymax; __syncthreads();
    for (int s = 128; s > 0; s >>= 1) {
        if (tid < s) red[tid] = fmaxf(red[tid], red[tid + s]);
        __syncthreads();
    }
    const float M = red[0]; __syncthreads();

    float mysum = 0.f;
    for (int t = tid; t < T_SEQ; t += 256) mysum += l[t] * expf(m[t] - M);
    red[tid] = mysum; __syncthreads();
    for (int s = 128; s > 0; s >>= 1) {
        if (tid < s) red[tid] += red[tid + s];
        __syncthreads();
    }
    const float Z = red[0];

    for (int t = tid; t < T_SEQ; t += 256) sc[t] = expf(m[t] - M) / Z;
}

// ---------------------------------------------------------------------------
// Kernel 4: out[b,t,d] = sum_{hk} attU[b,t,hk]*scale[b,hk/64,t] * Wo[hk,d]
// grid (D/64, B*T/64), block 256.
// ---------------------------------------------------------------------------
__global__ __launch_bounds__(256) void out_proj(
    const float* __restrict__ ws, const float* __restrict__ Wo,
    float* __restrict__ out)
{
    const int row0 = blockIdx.y * 64;     // over B*T
    const int col0 = blockIdx.x * 64;     // over D
    const int b = row0 / T_SEQ;
    const int t0 = row0 - b * T_SEQ;
    const float* attU = ws + ATT_OFF;
    const float* scb = ws + SC_OFF;

    __shared__ float As[64][17];
    __shared__ float Ws2[16][64];

    const int tid = threadIdx.x;
    const int tr0 = (tid >> 4) * 4;
    const int tc0 = (tid & 15) * 4;

    float acc[4][4] = {};

    for (int k0 = 0; k0 < NH * DK; k0 += 16) {
        const int h = k0 >> 6;
        {
            int r = tid >> 2, c = (tid & 3) * 4;
            float4 a4 = *(const float4*)&attU[(size_t)(row0 + r) * (NH * DK) + k0 + c];
            float scl = scb[((size_t)b * NH + h) * T_SEQ + t0 + r];
            As[r][c + 0] = a4.x * scl; As[r][c + 1] = a4.y * scl;
            As[r][c + 2] = a4.z * scl; As[r][c + 3] = a4.w * scl;
        }
        {
            int wr = tid >> 4, wc = (tid & 15) * 4;
            *(float4*)&Ws2[wr][wc] = *(const float4*)&Wo[(size_t)(k0 + wr) * D_MODEL + col0 + wc];
        }
        __syncthreads();
#pragma unroll
        for (int kk = 0; kk < 16; ++kk) {
            float a[4];
#pragma unroll
            for (int i = 0; i < 4; ++i) a[i] = As[tr0 + i][kk];
            float4 w4 = *(const float4*)&Ws2[kk][tc0];
            float w[4] = {w4.x, w4.y, w4.z, w4.w};
#pragma unroll
            for (int i = 0; i < 4; ++i)
#pragma unroll
                for (int j = 0; j < 4; ++j)
                    acc[i][j] = fmaf(a[i], w[j], acc[i][j]);
        }
        __syncthreads();
    }
#pragma unroll
    for (int i = 0; i < 4; ++i) {
        float4 o4 = make_float4(acc[i][0], acc[i][1], acc[i][2], acc[i][3]);
        *(float4*)&out[(size_t)(row0 + tr0 + i) * D_MODEL + col0 + tc0] = o4;
    }
}

// ---------------------------------------------------------------------------
extern "C" void kernel_launch(void* const* d_in, const int* in_sizes, int n_in,
                              void* d_out, int out_size, void* d_ws, size_t ws_size,
                              hipStream_t stream)
{
    const float* query = (const float*)d_in[0];
    const float* value = (const float*)d_in[1];
    const float* Wq = (const float*)d_in[2];
    const float* Wk = (const float*)d_in[3];
    const float* Wv = (const float*)d_in[4];
    const float* Wo = (const float*)d_in[5];
    const int* ls = (const int*)d_in[6];
    float* out = (float*)d_out;
    float* ws = (float*)d_ws;

    dim3 g1(T_SEQ / 64, 2 * NH, 3);
    proj_qkv<<<g1, 256, 0, stream>>>(query, value, Wq, Wk, Wv, ws);

    dim3 g2(T_SEQ / 64, 2 * NH);
    attn_fwd<<<g2, 256, 0, stream>>>(ws, ls, ws);

    softmax_stats<<<dim3(2 * NH), 256, 0, stream>>>(ws);

    dim3 g4(D_MODEL / 64, 2 * T_SEQ / 64);
    out_proj<<<g4, 256, 0, stream>>>(ws, Wo, out);
}

// Round 2
// 422.279 us; speedup vs baseline: 2.0717x; 2.0717x over previous
//
#include <hip/hip_runtime.h>
#include <math.h>

#define T_SEQ  2048
#define D_MODEL 512
#define NH     8
#define DK     64
#define NKB    (T_SEQ / 64)   // 32 key blocks

// workspace layout in floats
#define Q_OFF   0
#define K_OFF   2097152              // B*H*T*DK
#define V_OFF   (2 * 2097152)
#define ATT_OFF (3 * 2097152)        // [B, T, H*DK] unnormalized
#define M_OFF   (4 * 2097152)        // [B*H, T]
#define L_OFF   (M_OFF + 32768)
#define SC_OFF  (L_OFF + 32768)

// ---------------------------------------------------------------------------
// Kernel 1: QKV projections.  q[b,h,t,k] = sum_d in[b,t,d] * W[h,d,k]
// grid (T/64, B*H, 3), block 256.  64x64 output tile, 4x4 microtile.
// q additionally scaled by 1/sqrt(dk) = 0.125.
// ---------------------------------------------------------------------------
__global__ __launch_bounds__(256) void proj_qkv(
    const float* __restrict__ query, const float* __restrict__ value,
    const float* __restrict__ Wq, const float* __restrict__ Wk,
    const float* __restrict__ Wv, float* __restrict__ ws)
{
    const int which = blockIdx.z;            // 0=q 1=k 2=v
    const int bh = blockIdx.y;
    const int b = bh / NH, h = bh % NH;
    const int row0 = blockIdx.x * 64;

    const float* A = (which == 0 ? query : value) + (size_t)b * T_SEQ * D_MODEL;
    const float* W = (which == 0 ? Wq : (which == 1 ? Wk : Wv)) + (size_t)h * D_MODEL * DK;
    float* O = ws + (which == 0 ? Q_OFF : (which == 1 ? K_OFF : V_OFF))
                  + ((size_t)bh * T_SEQ + row0) * DK;
    const float outscale = (which == 0) ? 0.125f : 1.0f;

    __shared__ float As[64][17];
    __shared__ float Ws[16][64];

    const int tid = threadIdx.x;
    const int tr0 = (tid >> 4) * 4;
    const int tc0 = (tid & 15) * 4;

    float acc[4][4] = {};

    for (int d0 = 0; d0 < D_MODEL; d0 += 16) {
        {
            int r = tid >> 2, c = (tid & 3) * 4;
            float4 a4 = *(const float4*)&A[(size_t)(row0 + r) * D_MODEL + d0 + c];
            As[r][c + 0] = a4.x; As[r][c + 1] = a4.y;
            As[r][c + 2] = a4.z; As[r][c + 3] = a4.w;
        }
        {
            int wr = tid >> 4, wc = (tid & 15) * 4;
            *(float4*)&Ws[wr][wc] = *(const float4*)&W[(size_t)(d0 + wr) * DK + wc];
        }
        __syncthreads();
#pragma unroll
        for (int kk = 0; kk < 16; ++kk) {
            float a[4];
#pragma unroll
            for (int i = 0; i < 4; ++i) a[i] = As[tr0 + i][kk];
            float4 w4 = *(const float4*)&Ws[kk][tc0];
            float w[4] = {w4.x, w4.y, w4.z, w4.w};
#pragma unroll
            for (int i = 0; i < 4; ++i)
#pragma unroll
                for (int j = 0; j < 4; ++j)
                    acc[i][j] = fmaf(a[i], w[j], acc[i][j]);
        }
        __syncthreads();
    }
#pragma unroll
    for (int i = 0; i < 4; ++i) {
        float4 o4 = make_float4(acc[i][0] * outscale, acc[i][1] * outscale,
                                acc[i][2] * outscale, acc[i][3] * outscale);
        *(float4*)&O[(size_t)(tr0 + i) * DK + tc0] = o4;
    }
}

// ---------------------------------------------------------------------------
// Kernel 2: flash-style attention, unnormalized output + per-row (m, l).
// grid (T/64, B*H), block 256.
// LDS layouts chosen for conflict-free inner loops:
//   Qt[d][t], Kt[d][s]  (transposed, stride 64)  -> QK^T as outer product over d
//   Vs[s][d]            (row-major,  stride 64)  -> PV dot form, consecutive-lane reads
//   Ps[t][s]            (row-major,  stride 68)  -> broadcast reads land on 2 banks (free)
// ---------------------------------------------------------------------------
__global__ __launch_bounds__(256, 2) void attn_fwd(
    const float* __restrict__ ws_in, const int* __restrict__ ls_ptr,
    float* __restrict__ ws_out)
{
    const int bh = blockIdx.y;
    const int b = bh / NH, h = bh % NH;
    const int mtype = h >> 1;                 // 0=global 1=local 2=fwd 3=bwd
    const int row0 = blockIdx.x * 64;
    const int ls = *ls_ptr;

    const float* Q = ws_in + Q_OFF + ((size_t)bh * T_SEQ + row0) * DK;
    const float* K = ws_in + K_OFF + (size_t)bh * T_SEQ * DK;
    const float* V = ws_in + V_OFF + (size_t)bh * T_SEQ * DK;
    float* attU = ws_out + ATT_OFF;
    float* mrow = ws_out + M_OFF;
    float* lrow = ws_out + L_OFF;

    __shared__ float Qt[64][64];
    __shared__ float Kt[64][64];
    __shared__ float Vs[64][64];
    __shared__ float Ps[64][68];

    const int tid = threadIdx.x;
    const int rg = tid >> 4;          // 0..15
    const int cg = tid & 15;          // 0..15
    const int r0 = rg * 4, c0 = cg * 4;

    // transpose-loader indices: lane-per-row -> conflict-free column writes
    const int ldr = tid & 63;         // row 0..63
    const int ldc = (tid >> 6) * 16;  // col base 0,16,32,48

    // load Q tile transposed (Q pre-scaled by 0.125 in proj)
#pragma unroll
    for (int u = 0; u < 4; ++u) {
        int c = ldc + u * 4;
        float4 q4 = *(const float4*)&Q[(size_t)ldr * DK + c];
        Qt[c + 0][ldr] = q4.x; Qt[c + 1][ldr] = q4.y;
        Qt[c + 2][ldr] = q4.z; Qt[c + 3][ldr] = q4.w;
    }

    float m_i[4], l_i[4], O_acc[4][4];
#pragma unroll
    for (int i = 0; i < 4; ++i) {
        m_i[i] = -INFINITY; l_i[i] = 0.f;
#pragma unroll
        for (int j = 0; j < 4; ++j) O_acc[i][j] = 0.f;
    }

    int kb0 = 0, kb1 = NKB - 1;
    if (mtype == 1) {
        int lo = row0 - ls; if (lo < 0) lo = 0;
        int hi = row0 + 63 + ls; if (hi > T_SEQ - 1) hi = T_SEQ - 1;
        kb0 = lo >> 6; kb1 = hi >> 6;
    } else if (mtype == 2) {
        kb0 = row0 >> 6;
    } else if (mtype == 3) {
        kb1 = (row0 + 63) >> 6;
    }

    for (int kb = kb0; kb <= kb1; ++kb) {
        __syncthreads();   // previous PV done before overwriting Kt/Vs
        // V row-major (coalesced global, conflict-free LDS write)
#pragma unroll
        for (int it = 0; it < 4; ++it) {
            int f = tid + 256 * it;
            int r = f >> 4, c = (f & 15) * 4;
            *(float4*)&Vs[r][c] = *(const float4*)&V[(size_t)(kb * 64 + r) * DK + c];
        }
        // K transposed
#pragma unroll
        for (int u = 0; u < 4; ++u) {
            int c = ldc + u * 4;
            float4 k4 = *(const float4*)&K[(size_t)(kb * 64 + ldr) * DK + c];
            Kt[c + 0][ldr] = k4.x; Kt[c + 1][ldr] = k4.y;
            Kt[c + 2][ldr] = k4.z; Kt[c + 3][ldr] = k4.w;
        }
        __syncthreads();

        // S = Q K^T, outer product over d (Q pre-scaled)
        float s[4][4] = {};
#pragma unroll 4
        for (int d = 0; d < DK; ++d) {
            float4 qv = *(const float4*)&Qt[d][r0];
            float4 kv = *(const float4*)&Kt[d][c0];
            float q[4] = {qv.x, qv.y, qv.z, qv.w};
            float k[4] = {kv.x, kv.y, kv.z, kv.w};
#pragma unroll
            for (int i = 0; i < 4; ++i)
#pragma unroll
                for (int j = 0; j < 4; ++j)
                    s[i][j] = fmaf(q[i], k[j], s[i][j]);
        }

        // mask (only where the block can be partially masked)
        bool needmask;
        if (mtype == 0) needmask = false;
        else if (mtype == 2) needmask = (kb == kb0);
        else if (mtype == 3) needmask = (kb == kb1);
        else needmask = true;
        if (needmask) {
            const int ibase = row0 + r0, jbase = kb * 64 + c0;
#pragma unroll
            for (int i = 0; i < 4; ++i)
#pragma unroll
                for (int j = 0; j < 4; ++j) {
                    int ii = ibase + i, jj = jbase + j;
                    bool keep;
                    if (mtype == 1) keep = (ii - jj <= ls) && (jj - ii <= ls);
                    else if (mtype == 2) keep = (jj >= ii);
                    else keep = (jj <= ii);
                    if (!keep) s[i][j] = -INFINITY;
                }
        }

        // online softmax update, per row (16 lanes per row)
#pragma unroll
        for (int i = 0; i < 4; ++i) {
            float v = fmaxf(fmaxf(s[i][0], s[i][1]), fmaxf(s[i][2], s[i][3]));
#pragma unroll
            for (int off = 1; off < 16; off <<= 1)
                v = fmaxf(v, __shfl_xor(v, off, 16));
            float mn = fmaxf(m_i[i], v);
            float factor, p[4], psum;
            if (mn == -INFINITY) {
                factor = 1.f; p[0] = p[1] = p[2] = p[3] = 0.f; psum = 0.f;
            } else {
                factor = expf(m_i[i] - mn);   // m_i=-inf -> 0
#pragma unroll
                for (int j = 0; j < 4; ++j) p[j] = expf(s[i][j] - mn);
                psum = (p[0] + p[1]) + (p[2] + p[3]);
                m_i[i] = mn;
            }
#pragma unroll
            for (int off = 1; off < 16; off <<= 1)
                psum += __shfl_xor(psum, off, 16);
            l_i[i] = l_i[i] * factor + psum;
#pragma unroll
            for (int j = 0; j < 4; ++j) O_acc[i][j] *= factor;
#pragma unroll
            for (int j = 0; j < 4; ++j) Ps[r0 + i][c0 + j] = p[j];
        }
        __syncthreads();

        // O += P V  (pp: broadcast reads, vv: consecutive-lane reads)
#pragma unroll 2
        for (int c = 0; c < 64; c += 4) {
            float4 pp[4], vv[4];
#pragma unroll
            for (int i = 0; i < 4; ++i) pp[i] = *(const float4*)&Ps[r0 + i][c];
#pragma unroll
            for (int cc = 0; cc < 4; ++cc) vv[cc] = *(const float4*)&Vs[c + cc][c0];
#pragma unroll
            for (int i = 0; i < 4; ++i) {
                float pc[4] = {pp[i].x, pp[i].y, pp[i].z, pp[i].w};
#pragma unroll
                for (int cc = 0; cc < 4; ++cc) {
                    O_acc[i][0] = fmaf(pc[cc], vv[cc].x, O_acc[i][0]);
                    O_acc[i][1] = fmaf(pc[cc], vv[cc].y, O_acc[i][1]);
                    O_acc[i][2] = fmaf(pc[cc], vv[cc].z, O_acc[i][2]);
                    O_acc[i][3] = fmaf(pc[cc], vv[cc].w, O_acc[i][3]);
                }
            }
        }
    }

    // write unnormalized O to attU[b, t, h*64 + k], and (m,l)
#pragma unroll
    for (int i = 0; i < 4; ++i) {
        int t = row0 + r0 + i;
        float4 o4 = make_float4(O_acc[i][0], O_acc[i][1], O_acc[i][2], O_acc[i][3]);
        *(float4*)&attU[((size_t)b * T_SEQ + t) * (NH * DK) + h * DK + c0] = o4;
    }
    if (cg == 0) {
#pragma unroll
        for (int i = 0; i < 4; ++i) {
            int t = row0 + r0 + i;
            mrow[(size_t)bh * T_SEQ + t] = m_i[i];
            lrow[(size_t)bh * T_SEQ + t] = l_i[i];
        }
    }
}

// ---------------------------------------------------------------------------
// Kernel 3: per-(b,h) global reduce of (m,l) -> scale[t] = exp(m_t - M)/Z
// grid (B*H), block 256.
// ---------------------------------------------------------------------------
__global__ __launch_bounds__(256) void softmax_stats(float* __restrict__ ws)
{
    const int bh = blockIdx.x;
    const float* m = ws + M_OFF + (size_t)bh * T_SEQ;
    const float* l = ws + L_OFF + (size_t)bh * T_SEQ;
    float* sc = ws + SC_OFF + (size_t)bh * T_SEQ;

    __shared__ float red[256];
    const int tid = threadIdx.x;

    float mymax = -INFINITY;
    for (int t = tid; t < T_SEQ; t += 256) mymax = fmaxf(mymax, m[t]);
    red[tid] = mymax; __syncthreads();
    for (int s = 128; s > 0; s >>= 1) {
        if (tid < s) red[tid] = fmaxf(red[tid], red[tid + s]);
        __syncthreads();
    }
    const float M = red[0]; __syncthreads();

    float mysum = 0.f;
    for (int t = tid; t < T_SEQ; t += 256) mysum += l[t] * expf(m[t] - M);
    red[tid] = mysum; __syncthreads();
    for (int s = 128; s > 0; s >>= 1) {
        if (tid < s) red[tid] += red[tid + s];
        __syncthreads();
    }
    const float Z = red[0];

    for (int t = tid; t < T_SEQ; t += 256) sc[t] = expf(m[t] - M) / Z;
}

// ---------------------------------------------------------------------------
// Kernel 4: out[b,t,d] = sum_{hk} attU[b,t,hk]*scale[b,hk/64,t] * Wo[hk,d]
// grid (D/64, B*T/64), block 256.
// ---------------------------------------------------------------------------
__global__ __launch_bounds__(256) void out_proj(
    const float* __restrict__ ws, const float* __restrict__ Wo,
    float* __restrict__ out)
{
    const int row0 = blockIdx.y * 64;     // over B*T
    const int col0 = blockIdx.x * 64;     // over D
    const int b = row0 / T_SEQ;
    const int t0 = row0 - b * T_SEQ;
    const float* attU = ws + ATT_OFF;
    const float* scb = ws + SC_OFF;

    __shared__ float As[64][17];
    __shared__ float Ws2[16][64];

    const int tid = threadIdx.x;
    const int tr0 = (tid >> 4) * 4;
    const int tc0 = (tid & 15) * 4;

    float acc[4][4] = {};

    for (int k0 = 0; k0 < NH * DK; k0 += 16) {
        const int h = k0 >> 6;
        {
            int r = tid >> 2, c = (tid & 3) * 4;
            float4 a4 = *(const float4*)&attU[(size_t)(row0 + r) * (NH * DK) + k0 + c];
            float scl = scb[((size_t)b * NH + h) * T_SEQ + t0 + r];
            As[r][c + 0] = a4.x * scl; As[r][c + 1] = a4.y * scl;
            As[r][c + 2] = a4.z * scl; As[r][c + 3] = a4.w * scl;
        }
        {
            int wr = tid >> 4, wc = (tid & 15) * 4;
            *(float4*)&Ws2[wr][wc] = *(const float4*)&Wo[(size_t)(k0 + wr) * D_MODEL + col0 + wc];
        }
        __syncthreads();
#pragma unroll
        for (int kk = 0; kk < 16; ++kk) {
            float a[4];
#pragma unroll
            for (int i = 0; i < 4; ++i) a[i] = As[tr0 + i][kk];
            float4 w4 = *(const float4*)&Ws2[kk][tc0];
            float w[4] = {w4.x, w4.y, w4.z, w4.w};
#pragma unroll
            for (int i = 0; i < 4; ++i)
#pragma unroll
                for (int j = 0; j < 4; ++j)
                    acc[i][j] = fmaf(a[i], w[j], acc[i][j]);
        }
        __syncthreads();
    }
#pragma unroll
    for (int i = 0; i < 4; ++i) {
        float4 o4 = make_float4(acc[i][0], acc[i][1], acc[i][2], acc[i][3]);
        *(float4*)&out[(size_t)(row0 + tr0 + i) * D_MODEL + col0 + tc0] = o4;
    }
}

// ---------------------------------------------------------------------------
extern "C" void kernel_launch(void* const* d_in, const int* in_sizes, int n_in,
                              void* d_out, int out_size, void* d_ws, size_t ws_size,
                              hipStream_t stream)
{
    const float* query = (const float*)d_in[0];
    const float* value = (const float*)d_in[1];
    const float* Wq = (const float*)d_in[2];
    const float* Wk = (const float*)d_in[3];
    const float* Wv = (const float*)d_in[4];
    const float* Wo = (const float*)d_in[5];
    const int* ls = (const int*)d_in[6];
    float* out = (float*)d_out;
    float* ws = (float*)d_ws;

    dim3 g1(T_SEQ / 64, 2 * NH, 3);
    proj_qkv<<<g1, 256, 0, stream>>>(query, value, Wq, Wk, Wv, ws);

    dim3 g2(T_SEQ / 64, 2 * NH);
    attn_fwd<<<g2, 256, 0, stream>>>(ws, ls, ws);

    softmax_stats<<<dim3(2 * NH), 256, 0, stream>>>(ws);

    dim3 g4(D_MODEL / 64, 2 * T_SEQ / 64);
    out_proj<<<g4, 256, 0, stream>>>(ws, Wo, out);
}

// Round 3
// 414.802 us; speedup vs baseline: 2.1090x; 1.0180x over previous
//
#include <hip/hip_runtime.h>
#include <math.h>

#define T_SEQ  2048
#define D_MODEL 512
#define NH     8
#define DK     64
#define NKB    (T_SEQ / 64)   // 32 key blocks
#define BH     16             // B * NH
#define HK     (NH * DK)      // 512

// workspace layout in floats (head section fixed, tail depends on nch)
#define Q_OFF   0
#define K_OFF   2097152              // B*H*T*DK
#define V_OFF   (2 * 2097152)
#define ATT_OFF (3 * 2097152)        // nch slots of [B, T, H*DK] unnormalized
#define CHUNK_F 2097152              // floats per attP chunk slot
#define STAT_F  (BH * T_SEQ)         // 32768 floats per (m|l|sc) chunk slot

__device__ __forceinline__ size_t m_off(int nch) { return (size_t)ATT_OFF + (size_t)nch * CHUNK_F; }

// ---------------------------------------------------------------------------
// Kernel 1: QKV projections.  q[b,h,t,k] = sum_d in[b,t,d] * W[h,d,k]
// grid (T/64, B*H, 3), block 256.  64x64 output tile, 4x4 microtile.
// q additionally scaled by 1/sqrt(dk) = 0.125.
// ---------------------------------------------------------------------------
__global__ __launch_bounds__(256) void proj_qkv(
    const float* __restrict__ query, const float* __restrict__ value,
    const float* __restrict__ Wq, const float* __restrict__ Wk,
    const float* __restrict__ Wv, float* __restrict__ ws)
{
    const int which = blockIdx.z;            // 0=q 1=k 2=v
    const int bh = blockIdx.y;
    const int b = bh / NH, h = bh % NH;
    const int row0 = blockIdx.x * 64;

    const float* A = (which == 0 ? query : value) + (size_t)b * T_SEQ * D_MODEL;
    const float* W = (which == 0 ? Wq : (which == 1 ? Wk : Wv)) + (size_t)h * D_MODEL * DK;
    float* O = ws + (which == 0 ? Q_OFF : (which == 1 ? K_OFF : V_OFF))
                  + ((size_t)bh * T_SEQ + row0) * DK;
    const float outscale = (which == 0) ? 0.125f : 1.0f;

    __shared__ float As[64][17];
    __shared__ float Ws[16][64];

    const int tid = threadIdx.x;
    const int tr0 = (tid >> 4) * 4;
    const int tc0 = (tid & 15) * 4;

    float acc[4][4] = {};

    for (int d0 = 0; d0 < D_MODEL; d0 += 16) {
        {
            int r = tid >> 2, c = (tid & 3) * 4;
            float4 a4 = *(const float4*)&A[(size_t)(row0 + r) * D_MODEL + d0 + c];
            As[r][c + 0] = a4.x; As[r][c + 1] = a4.y;
            As[r][c + 2] = a4.z; As[r][c + 3] = a4.w;
        }
        {
            int wr = tid >> 4, wc = (tid & 15) * 4;
            *(float4*)&Ws[wr][wc] = *(const float4*)&W[(size_t)(d0 + wr) * DK + wc];
        }
        __syncthreads();
#pragma unroll
        for (int kk = 0; kk < 16; ++kk) {
            float a[4];
#pragma unroll
            for (int i = 0; i < 4; ++i) a[i] = As[tr0 + i][kk];
            float4 w4 = *(const float4*)&Ws[kk][tc0];
            float w[4] = {w4.x, w4.y, w4.z, w4.w};
#pragma unroll
            for (int i = 0; i < 4; ++i)
#pragma unroll
                for (int j = 0; j < 4; ++j)
                    acc[i][j] = fmaf(a[i], w[j], acc[i][j]);
        }
        __syncthreads();
    }
#pragma unroll
    for (int i = 0; i < 4; ++i) {
        float4 o4 = make_float4(acc[i][0] * outscale, acc[i][1] * outscale,
                                acc[i][2] * outscale, acc[i][3] * outscale);
        *(float4*)&O[(size_t)(tr0 + i) * DK + tc0] = o4;
    }
}

// ---------------------------------------------------------------------------
// Kernel 2: flash-style attention, split-K over `nch` chunks of `chb` key
// blocks.  grid (T/64, B*H, nch), block 256.  Per-chunk partial unnormalized
// O + per-row (m,l) written to the chunk's slot.  Next K/V tile prefetched
// into registers while the current tile computes.
// ---------------------------------------------------------------------------
__global__ __launch_bounds__(256, 2) void attn_fwd(
    const float* __restrict__ ws_in, const int* __restrict__ ls_ptr,
    float* __restrict__ ws_out, int chb, int nch)
{
    const int bh = blockIdx.y;
    const int b = bh / NH, h = bh % NH;
    const int mtype = h >> 1;                 // 0=global 1=local 2=fwd 3=bwd
    const int row0 = blockIdx.x * 64;
    const int rb = row0 >> 6;
    const int chunk = blockIdx.z;
    const int ls = *ls_ptr;

    float* mrow = ws_out + m_off(nch) + ((size_t)chunk * BH + bh) * T_SEQ;
    float* lrow = mrow + (size_t)nch * STAT_F;

    // full key-block range for this (mtype, row-block), then chunk intersect
    int lo = 0, hi = NKB - 1;
    if (mtype == 1) {
        int l2 = row0 - ls; if (l2 < 0) l2 = 0;
        int h2 = row0 + 63 + ls; if (h2 > T_SEQ - 1) h2 = T_SEQ - 1;
        lo = l2 >> 6; hi = h2 >> 6;
    } else if (mtype == 2) {
        lo = rb;
    } else if (mtype == 3) {
        hi = rb;
    }
    int kb0 = lo > chunk * chb ? lo : chunk * chb;
    int kb1 = hi < chunk * chb + chb - 1 ? hi : chunk * chb + chb - 1;

    const int tid = threadIdx.x;

    if (kb0 > kb1) {   // nothing to do for this chunk: mark empty, exit
        if (tid < 64) {
            mrow[row0 + tid] = -INFINITY;
            lrow[row0 + tid] = 0.f;
        }
        return;
    }

    const float* Q = ws_in + Q_OFF + ((size_t)bh * T_SEQ + row0) * DK;
    const float* K = ws_in + K_OFF + (size_t)bh * T_SEQ * DK;
    const float* V = ws_in + V_OFF + (size_t)bh * T_SEQ * DK;
    float* attP = ws_out + ATT_OFF + (size_t)chunk * CHUNK_F;

    __shared__ float Qt[64][64];
    __shared__ float Kt[64][64];
    __shared__ float Vs[64][64];
    __shared__ float Ps[64][68];

    const int rg = tid >> 4;          // 0..15
    const int cg = tid & 15;          // 0..15
    const int r0 = rg * 4, c0 = cg * 4;

    // transpose-loader indices: lane-per-row -> conflict-free column writes
    const int ldr = tid & 63;         // row 0..63
    const int ldc = (tid >> 6) * 16;  // col base 0,16,32,48
    // V loader indices
    const int vr = tid >> 4;          // 0..15 (+16*it)
    const int vc = (tid & 15) * 4;

    // load Q tile transposed (Q pre-scaled by 0.125 in proj)
#pragma unroll
    for (int u = 0; u < 4; ++u) {
        int c = ldc + u * 4;
        float4 q4 = *(const float4*)&Q[(size_t)ldr * DK + c];
        Qt[c + 0][ldr] = q4.x; Qt[c + 1][ldr] = q4.y;
        Qt[c + 2][ldr] = q4.z; Qt[c + 3][ldr] = q4.w;
    }

    float m_i[4], l_i[4], O_acc[4][4];
#pragma unroll
    for (int i = 0; i < 4; ++i) {
        m_i[i] = -INFINITY; l_i[i] = 0.f;
#pragma unroll
        for (int j = 0; j < 4; ++j) O_acc[i][j] = 0.f;
    }

    // prefetch first K/V tile into registers
    float4 kreg[4], vreg[4];
#pragma unroll
    for (int u = 0; u < 4; ++u)
        kreg[u] = *(const float4*)&K[(size_t)(kb0 * 64 + ldr) * DK + ldc + u * 4];
#pragma unroll
    for (int it = 0; it < 4; ++it)
        vreg[it] = *(const float4*)&V[(size_t)(kb0 * 64 + vr + 16 * it) * DK + vc];

    for (int kb = kb0; kb <= kb1; ++kb) {
        __syncthreads();   // previous PV done before overwriting Kt/Vs
        // stage registers -> LDS
#pragma unroll
        for (int it = 0; it < 4; ++it)
            *(float4*)&Vs[vr + 16 * it][vc] = vreg[it];
#pragma unroll
        for (int u = 0; u < 4; ++u) {
            int c = ldc + u * 4;
            Kt[c + 0][ldr] = kreg[u].x; Kt[c + 1][ldr] = kreg[u].y;
            Kt[c + 2][ldr] = kreg[u].z; Kt[c + 3][ldr] = kreg[u].w;
        }
        // issue next tile's loads (latency hides under this tile's compute)
        if (kb < kb1) {
#pragma unroll
            for (int u = 0; u < 4; ++u)
                kreg[u] = *(const float4*)&K[(size_t)((kb + 1) * 64 + ldr) * DK + ldc + u * 4];
#pragma unroll
            for (int it = 0; it < 4; ++it)
                vreg[it] = *(const float4*)&V[(size_t)((kb + 1) * 64 + vr + 16 * it) * DK + vc];
        }
        __syncthreads();

        // S = Q K^T, outer product over d (Q pre-scaled)
        float s[4][4] = {};
#pragma unroll 4
        for (int d = 0; d < DK; ++d) {
            float4 qv = *(const float4*)&Qt[d][r0];
            float4 kv = *(const float4*)&Kt[d][c0];
            float q[4] = {qv.x, qv.y, qv.z, qv.w};
            float k[4] = {kv.x, kv.y, kv.z, kv.w};
#pragma unroll
            for (int i = 0; i < 4; ++i)
#pragma unroll
                for (int j = 0; j < 4; ++j)
                    s[i][j] = fmaf(q[i], k[j], s[i][j]);
        }

        // mask (only where the block can be partially masked)
        bool needmask;
        if (mtype == 0) needmask = false;
        else if (mtype == 1) needmask = true;
        else needmask = (kb == rb);          // diagonal block for fwd/bwd
        if (needmask) {
            const int ibase = row0 + r0, jbase = kb * 64 + c0;
#pragma unroll
            for (int i = 0; i < 4; ++i)
#pragma unroll
                for (int j = 0; j < 4; ++j) {
                    int ii = ibase + i, jj = jbase + j;
                    bool keep;
                    if (mtype == 1) keep = (ii - jj <= ls) && (jj - ii <= ls);
                    else if (mtype == 2) keep = (jj >= ii);
                    else keep = (jj <= ii);
                    if (!keep) s[i][j] = -INFINITY;
                }
        }

        // online softmax update, per row (16 lanes per row)
#pragma unroll
        for (int i = 0; i < 4; ++i) {
            float v = fmaxf(fmaxf(s[i][0], s[i][1]), fmaxf(s[i][2], s[i][3]));
#pragma unroll
            for (int off = 1; off < 16; off <<= 1)
                v = fmaxf(v, __shfl_xor(v, off, 16));
            float mn = fmaxf(m_i[i], v);
            float factor, p[4], psum;
            if (mn == -INFINITY) {
                factor = 1.f; p[0] = p[1] = p[2] = p[3] = 0.f; psum = 0.f;
            } else {
                factor = expf(m_i[i] - mn);   // m_i=-inf -> 0
#pragma unroll
                for (int j = 0; j < 4; ++j) p[j] = expf(s[i][j] - mn);
                psum = (p[0] + p[1]) + (p[2] + p[3]);
                m_i[i] = mn;
            }
#pragma unroll
            for (int off = 1; off < 16; off <<= 1)
                psum += __shfl_xor(psum, off, 16);
            l_i[i] = l_i[i] * factor + psum;
#pragma unroll
            for (int j = 0; j < 4; ++j) O_acc[i][j] *= factor;
#pragma unroll
            for (int j = 0; j < 4; ++j) Ps[r0 + i][c0 + j] = p[j];
        }
        __syncthreads();

        // O += P V  (pp: broadcast reads, vv: consecutive-lane reads)
#pragma unroll 2
        for (int c = 0; c < 64; c += 4) {
            float4 pp[4], vv[4];
#pragma unroll
            for (int i = 0; i < 4; ++i) pp[i] = *(const float4*)&Ps[r0 + i][c];
#pragma unroll
            for (int cc = 0; cc < 4; ++cc) vv[cc] = *(const float4*)&Vs[c + cc][c0];
#pragma unroll
            for (int i = 0; i < 4; ++i) {
                float pc[4] = {pp[i].x, pp[i].y, pp[i].z, pp[i].w};
#pragma unroll
                for (int cc = 0; cc < 4; ++cc) {
                    O_acc[i][0] = fmaf(pc[cc], vv[cc].x, O_acc[i][0]);
                    O_acc[i][1] = fmaf(pc[cc], vv[cc].y, O_acc[i][1]);
                    O_acc[i][2] = fmaf(pc[cc], vv[cc].z, O_acc[i][2]);
                    O_acc[i][3] = fmaf(pc[cc], vv[cc].w, O_acc[i][3]);
                }
            }
        }
    }

    // write partial unnormalized O to attP[b, t, h*64 + k], and (m,l)
#pragma unroll
    for (int i = 0; i < 4; ++i) {
        int t = row0 + r0 + i;
        float4 o4 = make_float4(O_acc[i][0], O_acc[i][1], O_acc[i][2], O_acc[i][3]);
        *(float4*)&attP[((size_t)b * T_SEQ + t) * HK + h * DK + c0] = o4;
    }
    if (cg == 0) {
#pragma unroll
        for (int i = 0; i < 4; ++i) {
            int t = row0 + r0 + i;
            mrow[t] = m_i[i];
            lrow[t] = l_i[i];
        }
    }
}

// ---------------------------------------------------------------------------
// Kernel 3: per-(b,h) reduce of (m,l) over chunks+rows ->
// scale[c][t] = exp(m[c][t] - M)/Z.  grid (B*H), block 256.
// ---------------------------------------------------------------------------
__global__ __launch_bounds__(256) void softmax_stats(float* __restrict__ ws, int nch)
{
    const int bh = blockIdx.x;
    float* mbase = ws + m_off(nch);
    float* lbase = mbase + (size_t)nch * STAT_F;
    float* sbase = lbase + (size_t)nch * STAT_F;

    __shared__ float red[256];
    const int tid = threadIdx.x;
    const int n = nch * T_SEQ;

    float mymax = -INFINITY;
    for (int i = tid; i < n; i += 256) {
        int c = i >> 11, t = i & 2047;
        mymax = fmaxf(mymax, mbase[((size_t)c * BH + bh) * T_SEQ + t]);
    }
    red[tid] = mymax; __syncthreads();
    for (int s = 128; s > 0; s >>= 1) {
        if (tid < s) red[tid] = fmaxf(red[tid], red[tid + s]);
        __syncthreads();
    }
    const float M = red[0]; __syncthreads();

    float mysum = 0.f;
    for (int i = tid; i < n; i += 256) {
        int c = i >> 11, t = i & 2047;
        size_t idx = ((size_t)c * BH + bh) * T_SEQ + t;
        mysum += lbase[idx] * expf(mbase[idx] - M);
    }
    red[tid] = mysum; __syncthreads();
    for (int s = 128; s > 0; s >>= 1) {
        if (tid < s) red[tid] += red[tid + s];
        __syncthreads();
    }
    const float Z = red[0];

    for (int i = tid; i < n; i += 256) {
        int c = i >> 11, t = i & 2047;
        size_t idx = ((size_t)c * BH + bh) * T_SEQ + t;
        sbase[idx] = expf(mbase[idx] - M) / Z;
    }
}

// ---------------------------------------------------------------------------
// Kernel 4: out[b,t,d] = sum_c sum_{hk} attP[c][b,t,hk]*scale[c][b,h,t] * Wo[hk,d]
// grid (D/64, B*T/64), block 256.
// ---------------------------------------------------------------------------
__global__ __launch_bounds__(256) void out_proj(
    const float* __restrict__ ws, const float* __restrict__ Wo,
    float* __restrict__ out, int nch)
{
    const int row0 = blockIdx.y * 64;     // over B*T
    const int col0 = blockIdx.x * 64;     // over D
    const int b = row0 / T_SEQ;
    const int t0 = row0 - b * T_SEQ;
    const float* attP = ws + ATT_OFF;
    const float* scb = ws + m_off(nch) + 2 * (size_t)nch * STAT_F;

    __shared__ float As[64][17];
    __shared__ float Ws2[16][64];

    const int tid = threadIdx.x;
    const int tr0 = (tid >> 4) * 4;
    const int tc0 = (tid & 15) * 4;

    float acc[4][4] = {};

    for (int k0 = 0; k0 < HK; k0 += 16) {
        const int h = k0 >> 6;
        {
            int r = tid >> 2, c = (tid & 3) * 4;
            float a0 = 0.f, a1 = 0.f, a2 = 0.f, a3 = 0.f;
            for (int ch = 0; ch < nch; ++ch) {
                float4 a4 = *(const float4*)&attP[(size_t)ch * CHUNK_F +
                                                  (size_t)(row0 + r) * HK + k0 + c];
                float scl = scb[((size_t)ch * BH + b * NH + h) * T_SEQ + t0 + r];
                a0 = fmaf(a4.x, scl, a0); a1 = fmaf(a4.y, scl, a1);
                a2 = fmaf(a4.z, scl, a2); a3 = fmaf(a4.w, scl, a3);
            }
            As[r][c + 0] = a0; As[r][c + 1] = a1;
            As[r][c + 2] = a2; As[r][c + 3] = a3;
        }
        {
            int wr = tid >> 4, wc = (tid & 15) * 4;
            *(float4*)&Ws2[wr][wc] = *(const float4*)&Wo[(size_t)(k0 + wr) * D_MODEL + col0 + wc];
        }
        __syncthreads();
#pragma unroll
        for (int kk = 0; kk < 16; ++kk) {
            float a[4];
#pragma unroll
            for (int i = 0; i < 4; ++i) a[i] = As[tr0 + i][kk];
            float4 w4 = *(const float4*)&Ws2[kk][tc0];
            float w[4] = {w4.x, w4.y, w4.z, w4.w};
#pragma unroll
            for (int i = 0; i < 4; ++i)
#pragma unroll
                for (int j = 0; j < 4; ++j)
                    acc[i][j] = fmaf(a[i], w[j], acc[i][j]);
        }
        __syncthreads();
    }
#pragma unroll
    for (int i = 0; i < 4; ++i) {
        float4 o4 = make_float4(acc[i][0], acc[i][1], acc[i][2], acc[i][3]);
        *(float4*)&out[(size_t)(row0 + tr0 + i) * D_MODEL + col0 + tc0] = o4;
    }
}

// ---------------------------------------------------------------------------
extern "C" void kernel_launch(void* const* d_in, const int* in_sizes, int n_in,
                              void* d_out, int out_size, void* d_ws, size_t ws_size,
                              hipStream_t stream)
{
    const float* query = (const float*)d_in[0];
    const float* value = (const float*)d_in[1];
    const float* Wq = (const float*)d_in[2];
    const float* Wk = (const float*)d_in[3];
    const float* Wv = (const float*)d_in[4];
    const float* Wo = (const float*)d_in[5];
    const int* ls = (const int*)d_in[6];
    float* out = (float*)d_out;
    float* ws = (float*)d_ws;

    // nch=4 needs ATT_OFF + 4*CHUNK_F + 12*STAT_F floats; fall back to 1 chunk
    const size_t need4 = ((size_t)ATT_OFF + 4 * (size_t)CHUNK_F + 12 * (size_t)STAT_F) * 4;
    const int nch = (ws_size >= need4) ? 4 : 1;
    const int chb = NKB / nch;

    dim3 g1(T_SEQ / 64, BH, 3);
    proj_qkv<<<g1, 256, 0, stream>>>(query, value, Wq, Wk, Wv, ws);

    dim3 g2(T_SEQ / 64, BH, nch);
    attn_fwd<<<g2, 256, 0, stream>>>(ws, ls, ws, chb, nch);

    softmax_stats<<<dim3(BH), 256, 0, stream>>>(ws, nch);

    dim3 g4(D_MODEL / 64, 2 * T_SEQ / 64);
    out_proj<<<g4, 256, 0, stream>>>(ws, Wo, out, nch);
}

// Round 4
// 264.456 us; speedup vs baseline: 3.3080x; 1.5685x over previous
//
#include <hip/hip_runtime.h>
#include <hip/hip_bf16.h>
#include <math.h>

#define T_SEQ  2048
#define D_MODEL 512
#define NH     8
#define DK     64
#define NKB    (T_SEQ / 64)   // 32 key blocks
#define BH     16             // B * NH
#define HK     (NH * DK)      // 512

// workspace layout in floats
#define Q_OFF   0
#define K_OFF   2097152              // B*H*T*DK
#define V_OFF   (2 * 2097152)
#define ATT_OFF (3 * 2097152)        // nch slots of [B, T, H*DK] unnormalized
#define CHUNK_F 2097152              // floats per attP chunk slot
#define STAT_F  (BH * T_SEQ)         // 32768 floats per (m|l|sc) chunk slot
#define ATTS_OFF Q_OFF               // reduced attS reuses the dead Q buffer

typedef __attribute__((ext_vector_type(8))) short bf16x8;
typedef __attribute__((ext_vector_type(4))) float f32x4;

// ---- fp32 <-> bf16 split helpers (RNE) ----
static __device__ __forceinline__ unsigned short f2bu(float f) {
    union { float f; unsigned int u; } v; v.f = f;
    unsigned int u = v.u;
    unsigned int r = (u + 0x7FFFu + ((u >> 16) & 1u)) >> 16;
    return (unsigned short)r;
}
static __device__ __forceinline__ float bu2f(unsigned short h) {
    union { unsigned int u; float f; } v; v.u = ((unsigned int)h) << 16;
    return v.f;
}
// pack two floats into bf16-hi pair and bf16-lo (residual) pair
static __device__ __forceinline__ void split2(float a, float b,
                                              unsigned int& hi, unsigned int& lo) {
    unsigned short ha = f2bu(a), hb = f2bu(b);
    unsigned short la = f2bu(a - bu2f(ha)), lb = f2bu(b - bu2f(hb));
    hi = (unsigned int)ha | ((unsigned int)hb << 16);
    lo = (unsigned int)la | ((unsigned int)lb << 16);
}

// ---------------------------------------------------------------------------
// Kernel 1: QKV projections (SIMT fp32).  q scaled by 1/sqrt(dk)=0.125.
// grid (T/64, B*H, 3), block 256.
// ---------------------------------------------------------------------------
__global__ __launch_bounds__(256) void proj_qkv(
    const float* __restrict__ query, const float* __restrict__ value,
    const float* __restrict__ Wq, const float* __restrict__ Wk,
    const float* __restrict__ Wv, float* __restrict__ ws)
{
    const int which = blockIdx.z;            // 0=q 1=k 2=v
    const int bh = blockIdx.y;
    const int b = bh / NH, h = bh % NH;
    const int row0 = blockIdx.x * 64;

    const float* A = (which == 0 ? query : value) + (size_t)b * T_SEQ * D_MODEL;
    const float* W = (which == 0 ? Wq : (which == 1 ? Wk : Wv)) + (size_t)h * D_MODEL * DK;
    float* O = ws + (which == 0 ? Q_OFF : (which == 1 ? K_OFF : V_OFF))
                  + ((size_t)bh * T_SEQ + row0) * DK;
    const float outscale = (which == 0) ? 0.125f : 1.0f;

    __shared__ float As[64][17];
    __shared__ float Ws[16][64];

    const int tid = threadIdx.x;
    const int tr0 = (tid >> 4) * 4;
    const int tc0 = (tid & 15) * 4;

    float acc[4][4] = {};

    for (int d0 = 0; d0 < D_MODEL; d0 += 16) {
        {
            int r = tid >> 2, c = (tid & 3) * 4;
            float4 a4 = *(const float4*)&A[(size_t)(row0 + r) * D_MODEL + d0 + c];
            As[r][c + 0] = a4.x; As[r][c + 1] = a4.y;
            As[r][c + 2] = a4.z; As[r][c + 3] = a4.w;
        }
        {
            int wr = tid >> 4, wc = (tid & 15) * 4;
            *(float4*)&Ws[wr][wc] = *(const float4*)&W[(size_t)(d0 + wr) * DK + wc];
        }
        __syncthreads();
#pragma unroll
        for (int kk = 0; kk < 16; ++kk) {
            float a[4];
#pragma unroll
            for (int i = 0; i < 4; ++i) a[i] = As[tr0 + i][kk];
            float4 w4 = *(const float4*)&Ws[kk][tc0];
            float w[4] = {w4.x, w4.y, w4.z, w4.w};
#pragma unroll
            for (int i = 0; i < 4; ++i)
#pragma unroll
                for (int j = 0; j < 4; ++j)
                    acc[i][j] = fmaf(a[i], w[j], acc[i][j]);
        }
        __syncthreads();
    }
#pragma unroll
    for (int i = 0; i < 4; ++i) {
        float4 o4 = make_float4(acc[i][0] * outscale, acc[i][1] * outscale,
                                acc[i][2] * outscale, acc[i][3] * outscale);
        *(float4*)&O[(size_t)(tr0 + i) * DK + tc0] = o4;
    }
}

// ---------------------------------------------------------------------------
// Kernel 2: flash attention via 3x-bf16-split MFMA, split-K over nch chunks.
// grid (T/64, B*H, nch), block 256 (4 waves; wave w owns t-strip w*16..+15).
//   S^T = mfma(A=K, B=Q): C-layout -> t = lane&15  (row softmax mostly in-lane)
//   P stored t-major bf16 hi/lo; V stored TRANSPOSED (Vt[dk][s]) so PV's
//   B-frags are row-major b128 reads.  O accumulates fp32 in MFMA C regs.
// ---------------------------------------------------------------------------
__global__ __launch_bounds__(256, 2) void attn_fwd(
    const float* __restrict__ ws_in, const int* __restrict__ ls_ptr,
    float* __restrict__ ws_out, int chb, int nch)
{
    const int bh = blockIdx.y;
    const int b = bh / NH, h = bh % NH;
    const int mtype = h >> 1;                 // 0=global 1=local 2=fwd 3=bwd
    const int row0 = blockIdx.x * 64;
    const int rb = row0 >> 6;
    const int chunk = blockIdx.z;
    const int ls = *ls_ptr;

    float* mrow = ws_out + ATT_OFF + (size_t)nch * CHUNK_F + ((size_t)chunk * BH + bh) * T_SEQ;
    float* lrow = mrow + (size_t)nch * STAT_F;

    // full key-block range for this (mtype, row-block), then chunk intersect
    int lo = 0, hi = NKB - 1;
    if (mtype == 1) {
        int l2 = row0 - ls; if (l2 < 0) l2 = 0;
        int h2 = row0 + 63 + ls; if (h2 > T_SEQ - 1) h2 = T_SEQ - 1;
        lo = l2 >> 6; hi = h2 >> 6;
    } else if (mtype == 2) {
        lo = rb;
    } else if (mtype == 3) {
        hi = rb;
    }
    int kb0 = lo > chunk * chb ? lo : chunk * chb;
    int kb1 = hi < chunk * chb + chb - 1 ? hi : chunk * chb + chb - 1;

    const int tid = threadIdx.x;

    if (kb0 > kb1) {   // empty chunk: mark and exit
        if (tid < 64) {
            mrow[row0 + tid] = -INFINITY;
            lrow[row0 + tid] = 0.f;
        }
        return;
    }

    const float* Q = ws_in + Q_OFF + ((size_t)bh * T_SEQ + row0) * DK;
    const float* K = ws_in + K_OFF + (size_t)bh * T_SEQ * DK;
    const float* V = ws_in + V_OFF + (size_t)bh * T_SEQ * DK;
    float* attP = ws_out + ATT_OFF + (size_t)chunk * CHUNK_F;

    // bf16 hi/lo tiles; stride 72 keeps 16B alignment (144B rows) and 2-way-max banks
    __shared__ unsigned short Qhi[64][72], Qlo[64][72];
    __shared__ unsigned short Khi[64][72], Klo[64][72];
    __shared__ unsigned short Vthi[64][72], Vtlo[64][72];   // transposed: [dk][s]
    __shared__ unsigned short Phi[64][72], Plo[64][72];     // [t][s]

    const int lane = tid & 63;
    const int w = tid >> 6;           // wave id: t-strip base w*16
    const int lr = lane & 15;
    const int lg = lane >> 4;

    // staging thread maps
    const int krow = tid >> 2, kd0 = (tid & 3) * 16;   // K/Q: row, 16-wide d slice
    const int vs = tid & 63, vd0 = (tid >> 6) * 16;    // V: s row, 16-wide d slice

    // ---- stage Q (once) ----
    {
        float4 q[4];
#pragma unroll
        for (int i = 0; i < 4; ++i)
            q[i] = *(const float4*)&Q[(size_t)krow * DK + kd0 + i * 4];
        unsigned int h0, h1, h2, h3, l0, l1, l2, l3;
        split2(q[0].x, q[0].y, h0, l0); split2(q[0].z, q[0].w, h1, l1);
        split2(q[1].x, q[1].y, h2, l2); split2(q[1].z, q[1].w, h3, l3);
        *(uint4*)&Qhi[krow][kd0] = make_uint4(h0, h1, h2, h3);
        *(uint4*)&Qlo[krow][kd0] = make_uint4(l0, l1, l2, l3);
        split2(q[2].x, q[2].y, h0, l0); split2(q[2].z, q[2].w, h1, l1);
        split2(q[3].x, q[3].y, h2, l2); split2(q[3].z, q[3].w, h3, l3);
        *(uint4*)&Qhi[krow][kd0 + 8] = make_uint4(h0, h1, h2, h3);
        *(uint4*)&Qlo[krow][kd0 + 8] = make_uint4(l0, l1, l2, l3);
    }

    float m_i = -INFINITY, l_i = 0.f;
    f32x4 oacc[4];
#pragma unroll
    for (int n2 = 0; n2 < 4; ++n2) oacc[n2] = (f32x4){0.f, 0.f, 0.f, 0.f};

    // prefetch first K/V tile (f32) into registers
    float4 kreg[4], vreg[4];
#pragma unroll
    for (int i = 0; i < 4; ++i)
        kreg[i] = *(const float4*)&K[((size_t)kb0 * 64 + krow) * DK + kd0 + i * 4];
#pragma unroll
    for (int i = 0; i < 4; ++i)
        vreg[i] = *(const float4*)&V[((size_t)kb0 * 64 + vs) * DK + vd0 + i * 4];

    for (int kb = kb0; kb <= kb1; ++kb) {
        __syncthreads();   // prev QK (K) and PV (Vt) reads done

        // ---- stage K (row-major, packed b128 writes) ----
        {
            unsigned int h0, h1, h2, h3, l0, l1, l2, l3;
            split2(kreg[0].x, kreg[0].y, h0, l0); split2(kreg[0].z, kreg[0].w, h1, l1);
            split2(kreg[1].x, kreg[1].y, h2, l2); split2(kreg[1].z, kreg[1].w, h3, l3);
            *(uint4*)&Khi[krow][kd0] = make_uint4(h0, h1, h2, h3);
            *(uint4*)&Klo[krow][kd0] = make_uint4(l0, l1, l2, l3);
            split2(kreg[2].x, kreg[2].y, h0, l0); split2(kreg[2].z, kreg[2].w, h1, l1);
            split2(kreg[3].x, kreg[3].y, h2, l2); split2(kreg[3].z, kreg[3].w, h3, l3);
            *(uint4*)&Khi[krow][kd0 + 8] = make_uint4(h0, h1, h2, h3);
            *(uint4*)&Klo[krow][kd0 + 8] = make_uint4(l0, l1, l2, l3);
        }
        // ---- stage V transposed (scalar b16 writes, consecutive-s lanes) ----
#pragma unroll
        for (int i = 0; i < 4; ++i) {
            float xs[4] = {vreg[i].x, vreg[i].y, vreg[i].z, vreg[i].w};
#pragma unroll
            for (int e = 0; e < 4; ++e) {
                int d = vd0 + i * 4 + e;
                unsigned short hh = f2bu(xs[e]);
                Vthi[d][vs] = hh;
                Vtlo[d][vs] = f2bu(xs[e] - bu2f(hh));
            }
        }
        // issue next tile's global loads (hide under this tile's MFMA)
        if (kb < kb1) {
#pragma unroll
            for (int i = 0; i < 4; ++i)
                kreg[i] = *(const float4*)&K[((size_t)(kb + 1) * 64 + krow) * DK + kd0 + i * 4];
#pragma unroll
            for (int i = 0; i < 4; ++i)
                vreg[i] = *(const float4*)&V[((size_t)(kb + 1) * 64 + vs) * DK + vd0 + i * 4];
        }
        __syncthreads();

        // ---- QK: S^T[s][t] strip (all 64 s x 16 t) ----
        const unsigned short* qrh = &Qhi[w * 16 + lr][lg * 8];
        const unsigned short* qrl = &Qlo[w * 16 + lr][lg * 8];
        bf16x8 bqh0 = *(const bf16x8*)(qrh);
        bf16x8 bqh1 = *(const bf16x8*)(qrh + 32);
        bf16x8 bql0 = *(const bf16x8*)(qrl);
        bf16x8 bql1 = *(const bf16x8*)(qrl + 32);

        f32x4 sacc[4];
#pragma unroll
        for (int m = 0; m < 4; ++m) {
            const unsigned short* krh = &Khi[m * 16 + lr][lg * 8];
            const unsigned short* krl = &Klo[m * 16 + lr][lg * 8];
            bf16x8 ah0 = *(const bf16x8*)(krh);
            bf16x8 ah1 = *(const bf16x8*)(krh + 32);
            bf16x8 al0 = *(const bf16x8*)(krl);
            bf16x8 al1 = *(const bf16x8*)(krl + 32);
            f32x4 a = (f32x4){0.f, 0.f, 0.f, 0.f};
            a = __builtin_amdgcn_mfma_f32_16x16x32_bf16(ah0, bqh0, a, 0, 0, 0);
            a = __builtin_amdgcn_mfma_f32_16x16x32_bf16(ah1, bqh1, a, 0, 0, 0);
            a = __builtin_amdgcn_mfma_f32_16x16x32_bf16(ah0, bql0, a, 0, 0, 0);
            a = __builtin_amdgcn_mfma_f32_16x16x32_bf16(ah1, bql1, a, 0, 0, 0);
            a = __builtin_amdgcn_mfma_f32_16x16x32_bf16(al0, bqh0, a, 0, 0, 0);
            a = __builtin_amdgcn_mfma_f32_16x16x32_bf16(al1, bqh1, a, 0, 0, 0);
            sacc[m] = a;
        }

        // ---- mask + online softmax (t = lane&15 per lane; s spread in-lane) ----
        const int t_glob = row0 + w * 16 + lr;
        const bool needmask = (mtype == 1) || ((mtype >= 2) && (kb == rb));
        float p[4][4];
        float vmax = -INFINITY;
#pragma unroll
        for (int m = 0; m < 4; ++m)
#pragma unroll
            for (int r = 0; r < 4; ++r) {
                float x = sacc[m][r];
                if (needmask) {
                    int s_glob = kb * 64 + m * 16 + lg * 4 + r;
                    bool keep;
                    if (mtype == 1) keep = (t_glob - s_glob <= ls) && (s_glob - t_glob <= ls);
                    else if (mtype == 2) keep = (s_glob >= t_glob);
                    else keep = (s_glob <= t_glob);
                    if (!keep) x = -INFINITY;
                }
                p[m][r] = x;
                vmax = fmaxf(vmax, x);
            }
        vmax = fmaxf(vmax, __shfl_xor(vmax, 16, 64));
        vmax = fmaxf(vmax, __shfl_xor(vmax, 32, 64));
        float mn = fmaxf(m_i, vmax);
        float factor = 1.f, psum = 0.f;
        if (mn == -INFINITY) {
#pragma unroll
            for (int m = 0; m < 4; ++m)
#pragma unroll
                for (int r = 0; r < 4; ++r) p[m][r] = 0.f;
        } else {
            factor = expf(m_i - mn);   // m_i=-inf -> 0
            m_i = mn;
#pragma unroll
            for (int m = 0; m < 4; ++m)
#pragma unroll
                for (int r = 0; r < 4; ++r) {
                    p[m][r] = expf(p[m][r] - mn);
                    psum += p[m][r];
                }
        }
        psum += __shfl_xor(psum, 16, 64);
        psum += __shfl_xor(psum, 32, 64);
        l_i = l_i * factor + psum;

        // ---- store P (t-major) as bf16 hi/lo, packed b64 ----
#pragma unroll
        for (int m = 0; m < 4; ++m) {
            unsigned int ph01, pl01, ph23, pl23;
            split2(p[m][0], p[m][1], ph01, pl01);
            split2(p[m][2], p[m][3], ph23, pl23);
            *(uint2*)&Phi[w * 16 + lr][m * 16 + lg * 4] = make_uint2(ph01, ph23);
            *(uint2*)&Plo[w * 16 + lr][m * 16 + lg * 4] = make_uint2(pl01, pl23);
        }

        // ---- rescale O by factor (redistribute per-t factor to C-layout rows) ----
        float fr[4];
#pragma unroll
        for (int r = 0; r < 4; ++r) fr[r] = __shfl(factor, lg * 4 + r, 64);
#pragma unroll
        for (int n2 = 0; n2 < 4; ++n2)
#pragma unroll
            for (int r = 0; r < 4; ++r) oacc[n2][r] *= fr[r];

        // ---- PV: O[t][dk] += P * V  (A=P rows, B=Vt rows; same-wave P RAW) ----
        const unsigned short* prh = &Phi[w * 16 + lr][lg * 8];
        const unsigned short* prl = &Plo[w * 16 + lr][lg * 8];
        bf16x8 aph0 = *(const bf16x8*)(prh);
        bf16x8 aph1 = *(const bf16x8*)(prh + 32);
        bf16x8 apl0 = *(const bf16x8*)(prl);
        bf16x8 apl1 = *(const bf16x8*)(prl + 32);
#pragma unroll
        for (int n2 = 0; n2 < 4; ++n2) {
            const unsigned short* vrh = &Vthi[n2 * 16 + lr][lg * 8];
            const unsigned short* vrl = &Vtlo[n2 * 16 + lr][lg * 8];
            bf16x8 bh0 = *(const bf16x8*)(vrh);
            bf16x8 bh1 = *(const bf16x8*)(vrh + 32);
            bf16x8 bl0 = *(const bf16x8*)(vrl);
            bf16x8 bl1 = *(const bf16x8*)(vrl + 32);
            f32x4 a = oacc[n2];
            a = __builtin_amdgcn_mfma_f32_16x16x32_bf16(aph0, bh0, a, 0, 0, 0);
            a = __builtin_amdgcn_mfma_f32_16x16x32_bf16(aph1, bh1, a, 0, 0, 0);
            a = __builtin_amdgcn_mfma_f32_16x16x32_bf16(aph0, bl0, a, 0, 0, 0);
            a = __builtin_amdgcn_mfma_f32_16x16x32_bf16(aph1, bl1, a, 0, 0, 0);
            a = __builtin_amdgcn_mfma_f32_16x16x32_bf16(apl0, bh0, a, 0, 0, 0);
            a = __builtin_amdgcn_mfma_f32_16x16x32_bf16(apl1, bh1, a, 0, 0, 0);
            oacc[n2] = a;
        }
    }

    // ---- write partial unnormalized O and (m,l) ----
#pragma unroll
    for (int n2 = 0; n2 < 4; ++n2)
#pragma unroll
        for (int r = 0; r < 4; ++r) {
            int t = row0 + w * 16 + lg * 4 + r;
            attP[((size_t)b * T_SEQ + t) * HK + h * DK + n2 * 16 + lr] = oacc[n2][r];
        }
    if (lg == 0) {
        mrow[row0 + w * 16 + lr] = m_i;
        lrow[row0 + w * 16 + lr] = l_i;
    }
}

// ---------------------------------------------------------------------------
// Kernel 3: per-(b,h) reduce of (m,l) over chunks+rows ->
// scale[c][t] = exp(m[c][t] - M)/Z.  grid (B*H), block 256.
// ---------------------------------------------------------------------------
__global__ __launch_bounds__(256) void softmax_stats(float* __restrict__ ws, int nch)
{
    const int bh = blockIdx.x;
    float* mbase = ws + ATT_OFF + (size_t)nch * CHUNK_F;
    float* lbase = mbase + (size_t)nch * STAT_F;
    float* sbase = lbase + (size_t)nch * STAT_F;

    __shared__ float red[256];
    const int tid = threadIdx.x;
    const int n = nch * T_SEQ;

    float mymax = -INFINITY;
    for (int i = tid; i < n; i += 256) {
        int c = i >> 11, t = i & 2047;
        mymax = fmaxf(mymax, mbase[((size_t)c * BH + bh) * T_SEQ + t]);
    }
    red[tid] = mymax; __syncthreads();
    for (int s = 128; s > 0; s >>= 1) {
        if (tid < s) red[tid] = fmaxf(red[tid], red[tid + s]);
        __syncthreads();
    }
    const float M = red[0]; __syncthreads();

    float mysum = 0.f;
    for (int i = tid; i < n; i += 256) {
        int c = i >> 11, t = i & 2047;
        size_t idx = ((size_t)c * BH + bh) * T_SEQ + t;
        mysum += lbase[idx] * expf(mbase[idx] - M);
    }
    red[tid] = mysum; __syncthreads();
    for (int s = 128; s > 0; s >>= 1) {
        if (tid < s) red[tid] += red[tid + s];
        __syncthreads();
    }
    const float Z = red[0];

    for (int i = tid; i < n; i += 256) {
        int c = i >> 11, t = i & 2047;
        size_t idx = ((size_t)c * BH + bh) * T_SEQ + t;
        sbase[idx] = expf(mbase[idx] - M) / Z;
    }
}

// ---------------------------------------------------------------------------
// Kernel 3.5: attS[b,t,hk] = sum_c attP[c][b,t,hk] * scale[c][b,h,t]
// grid (B*T*HK/1024), block 256, float4 per thread.  attS reuses Q buffer.
// ---------------------------------------------------------------------------
__global__ __launch_bounds__(256) void reduce_chunks(float* __restrict__ ws, int nch)
{
    const size_t flat = ((size_t)blockIdx.x * 256 + threadIdx.x) * 4;
    const float* attP = ws + ATT_OFF;
    const float* scb = ws + ATT_OFF + (size_t)nch * CHUNK_F + 2 * (size_t)nch * STAT_F;
    float* attS = ws + ATTS_OFF;

    const int hk = (int)(flat & (HK - 1));
    const size_t bt = flat / HK;
    const int b = (int)(bt >> 11), t = (int)(bt & 2047);
    const int h = hk >> 6;

    float4 acc = make_float4(0.f, 0.f, 0.f, 0.f);
    for (int c = 0; c < nch; ++c) {
        float4 a = *(const float4*)&attP[(size_t)c * CHUNK_F + flat];
        float scl = scb[((size_t)c * BH + b * NH + h) * T_SEQ + t];
        acc.x = fmaf(a.x, scl, acc.x); acc.y = fmaf(a.y, scl, acc.y);
        acc.z = fmaf(a.z, scl, acc.z); acc.w = fmaf(a.w, scl, acc.w);
    }
    *(float4*)&attS[flat] = acc;
}

// ---------------------------------------------------------------------------
// Kernel 4: out[b,t,d] = sum_hk attS[b,t,hk] * Wo[hk,d]
// grid (D/64, B*T/64), block 256.
// ---------------------------------------------------------------------------
__global__ __launch_bounds__(256) void out_proj(
    const float* __restrict__ ws, const float* __restrict__ Wo,
    float* __restrict__ out)
{
    const int row0 = blockIdx.y * 64;     // over B*T
    const int col0 = blockIdx.x * 64;     // over D
    const float* attS = ws + ATTS_OFF;

    __shared__ float As[64][17];
    __shared__ float Ws2[16][64];

    const int tid = threadIdx.x;
    const int tr0 = (tid >> 4) * 4;
    const int tc0 = (tid & 15) * 4;

    float acc[4][4] = {};

    for (int k0 = 0; k0 < HK; k0 += 16) {
        {
            int r = tid >> 2, c = (tid & 3) * 4;
            float4 a4 = *(const float4*)&attS[(size_t)(row0 + r) * HK + k0 + c];
            As[r][c + 0] = a4.x; As[r][c + 1] = a4.y;
            As[r][c + 2] = a4.z; As[r][c + 3] = a4.w;
        }
        {
            int wr = tid >> 4, wc = (tid & 15) * 4;
            *(float4*)&Ws2[wr][wc] = *(const float4*)&Wo[(size_t)(k0 + wr) * D_MODEL + col0 + wc];
        }
        __syncthreads();
#pragma unroll
        for (int kk = 0; kk < 16; ++kk) {
            float a[4];
#pragma unroll
            for (int i = 0; i < 4; ++i) a[i] = As[tr0 + i][kk];
            float4 w4 = *(const float4*)&Ws2[kk][tc0];
            float w[4] = {w4.x, w4.y, w4.z, w4.w};
#pragma unroll
            for (int i = 0; i < 4; ++i)
#pragma unroll
                for (int j = 0; j < 4; ++j)
                    acc[i][j] = fmaf(a[i], w[j], acc[i][j]);
        }
        __syncthreads();
    }
#pragma unroll
    for (int i = 0; i < 4; ++i) {
        float4 o4 = make_float4(acc[i][0], acc[i][1], acc[i][2], acc[i][3]);
        *(float4*)&out[(size_t)(row0 + tr0 + i) * D_MODEL + col0 + tc0] = o4;
    }
}

// ---------------------------------------------------------------------------
extern "C" void kernel_launch(void* const* d_in, const int* in_sizes, int n_in,
                              void* d_out, int out_size, void* d_ws, size_t ws_size,
                              hipStream_t stream)
{
    const float* query = (const float*)d_in[0];
    const float* value = (const float*)d_in[1];
    const float* Wq = (const float*)d_in[2];
    const float* Wk = (const float*)d_in[3];
    const float* Wv = (const float*)d_in[4];
    const float* Wo = (const float*)d_in[5];
    const int* ls = (const int*)d_in[6];
    float* out = (float*)d_out;
    float* ws = (float*)d_ws;

    // nch=4 needs ATT_OFF + 4*CHUNK_F + 12*STAT_F floats; fall back to 1 chunk
    const size_t need4 = ((size_t)ATT_OFF + 4 * (size_t)CHUNK_F + 12 * (size_t)STAT_F) * 4;
    const int nch = (ws_size >= need4) ? 4 : 1;
    const int chb = NKB / nch;

    dim3 g1(T_SEQ / 64, BH, 3);
    proj_qkv<<<g1, 256, 0, stream>>>(query, value, Wq, Wk, Wv, ws);

    dim3 g2(T_SEQ / 64, BH, nch);
    attn_fwd<<<g2, 256, 0, stream>>>(ws, ls, ws, chb, nch);

    softmax_stats<<<dim3(BH), 256, 0, stream>>>(ws, nch);

    reduce_chunks<<<dim3((2 * T_SEQ * HK) / 1024), 256, 0, stream>>>(ws, nch);

    dim3 g4(D_MODEL / 64, 2 * T_SEQ / 64);
    out_proj<<<g4, 256, 0, stream>>>(ws, Wo, out);
}

// Round 5
// 140.583 us; speedup vs baseline: 6.2228x; 1.8811x over previous
//
#include <hip/hip_runtime.h>
#include <math.h>

#define T_SEQ  2048
#define D_MODEL 512
#define NH     8
#define DK     64
#define NKB    32
#define BH     16
#define HK     512
#define NCH    2
#define CHB    16
#define LOG2E  1.44269504088896340736f
#define QSCALE (0.125f * LOG2E)

typedef unsigned int uint;
typedef unsigned short ushort;
typedef __attribute__((ext_vector_type(8))) short bf16x8;
typedef __attribute__((ext_vector_type(4))) float f32x4;

// ---- workspace byte offsets ----
#define QHI_B   (0ull)
#define QLO_B   (QHI_B + 4194304ull)     // [bh][t][dk] ushort
#define KHI_B   (QLO_B + 4194304ull)
#define KLO_B   (KHI_B + 4194304ull)
#define VTHI_B  (KLO_B + 4194304ull)     // [bh][dk][t] ushort
#define VTLO_B  (VTHI_B + 4194304ull)
#define WTHI_B  (VTLO_B + 4194304ull)    // [which][h][k][d] ushort, 1572864 B
#define WTLO_B  (WTHI_B + 1572864ull)
#define WOTHI_B (WTLO_B + 1572864ull)    // [d][hk] ushort, 524288 B
#define WOTLO_B (WOTHI_B + 524288ull)
#define ATTP_B  (WOTLO_B + 524288ull)    // NCH x [b][t][hk] f32 (8 MB each)
#define CHUNK_F 2097152ull
#define MST_B   (ATTP_B + (ull_t)NCH * 8388608ull)
#define LST_B   (MST_B + 262144ull)      // NCH*BH*T f32
#define SST_B   (LST_B + 262144ull)
#define ATTSHI_B (SST_B + 262144ull)     // [bt][hk] ushort
#define ATTSLO_B (ATTSHI_B + 4194304ull)
typedef unsigned long long ull_t;

// truncation split: hi = bit-trunc bf16 of x; lo = bit-trunc bf16 of (x - hi).
// dropped error <= 2^-16 |x|; packs two values into one uint (lo16=a, hi16=b).
static __device__ __forceinline__ void tsplit2(float a, float b, uint& hi, uint& lo) {
    uint ua = __float_as_uint(a), ub = __float_as_uint(b);
    uint ha = ua & 0xFFFF0000u, hb = ub & 0xFFFF0000u;
    hi = (ha >> 16) | hb;
    float ra = a - __uint_as_float(ha);
    float rb = b - __uint_as_float(hb);
    lo = (__float_as_uint(ra) >> 16) | (__float_as_uint(rb) & 0xFFFF0000u);
}

// ---------------------------------------------------------------------------
// Kernel 0: weight prep.  Wq/Wk/Wv [h][d][k] -> Wt[which][h][k][d] hi/lo bf16;
// Wo [hk][d] -> Wot[d][hk] hi/lo.  grid 2048 x 256.
// ---------------------------------------------------------------------------
__global__ __launch_bounds__(256) void split_w(
    const float* __restrict__ Wq, const float* __restrict__ Wk,
    const float* __restrict__ Wv, const float* __restrict__ Wo,
    float* __restrict__ ws)
{
    uint* WTH = (uint*)((char*)ws + WTHI_B);
    uint* WTL = (uint*)((char*)ws + WTLO_B);
    uint* WOH = (uint*)((char*)ws + WOTHI_B);
    uint* WOL = (uint*)((char*)ws + WOTLO_B);
    const int gid = blockIdx.x * 256 + threadIdx.x;
    if (blockIdx.x < 1536) {
        const int d2 = gid & 255;
        const int k = (gid >> 8) & 63;
        const int h = (gid >> 14) & 7;
        const int which = gid >> 17;
        const float* W = (which == 0 ? Wq : (which == 1 ? Wk : Wv));
        const float* src = W + ((size_t)h * D_MODEL + 2 * d2) * DK + k;
        uint hi, lo;
        tsplit2(src[0], src[DK], hi, lo);
        const size_t o = (((size_t)(which * 8 + h) * 64 + k) * 512 + 2 * d2) >> 1;
        WTH[o] = hi; WTL[o] = lo;
    } else {
        const int o = gid - 1536 * 256;        // 0..131071
        const int hk2 = o & 255;
        const int d = o >> 8;
        const float* src = Wo + (size_t)(2 * hk2) * D_MODEL + d;
        uint hi, lo;
        tsplit2(src[0], src[D_MODEL], hi, lo);
        const size_t oo = ((size_t)d * 512 + 2 * hk2) >> 1;
        WOH[oo] = hi; WOL[oo] = lo;
    }
}

// ---------------------------------------------------------------------------
// Kernel 1: QKV projections via 3-term bf16-split MFMA.
// grid (T/64, BH, 3), block 256.  which<2: C^T[k][t] path -> Q/K planes
// [bh][t][dk]; which==2: C[s][k] path -> Vt planes [bh][dk][t].
// Q additionally scaled by 0.125*log2(e)  (softmax runs in base 2).
// ---------------------------------------------------------------------------
__global__ __launch_bounds__(256) void proj_mfma(
    const float* __restrict__ query, const float* __restrict__ value,
    float* __restrict__ ws)
{
    const int which = blockIdx.z;
    const int bh = blockIdx.y, b = bh >> 3, h = bh & 7;
    const int t0 = blockIdx.x * 64;
    const float* X = (which == 0 ? query : value) + (size_t)b * T_SEQ * D_MODEL;
    const ushort* WtH = (const ushort*)((char*)ws + WTHI_B) + (size_t)(which * 8 + h) * 64 * 512;
    const ushort* WtL = (const ushort*)((char*)ws + WTLO_B) + (size_t)(which * 8 + h) * 64 * 512;

    __shared__ ushort BsH[64][64], BsL[64][64];

    const int tid = threadIdx.x, lane = tid & 63, w = tid >> 6;
    const int lr = lane & 15, lg = lane >> 4;
    const int sg = tid & 7, srow = tid >> 3;
    const int swz0 = (sg ^ (srow & 7)) * 8;
    const int c0s = (lg ^ (lr & 7)) * 8, c1s = c0s ^ 32;

    f32x4 acc[4];
#pragma unroll
    for (int i = 0; i < 4; ++i) acc[i] = (f32x4){0.f, 0.f, 0.f, 0.f};

    for (int d0 = 0; d0 < D_MODEL; d0 += 64) {
        __syncthreads();
        *(uint4*)&BsH[srow][swz0]      = *(const uint4*)&WtH[(size_t)srow * 512 + d0 + sg * 8];
        *(uint4*)&BsH[srow + 32][swz0] = *(const uint4*)&WtH[(size_t)(srow + 32) * 512 + d0 + sg * 8];
        *(uint4*)&BsL[srow][swz0]      = *(const uint4*)&WtL[(size_t)srow * 512 + d0 + sg * 8];
        *(uint4*)&BsL[srow + 32][swz0] = *(const uint4*)&WtL[(size_t)(srow + 32) * 512 + d0 + sg * 8];
        __syncthreads();

        // X fragments (global, split in-register)
        const float* xr = &X[(size_t)(t0 + w * 16 + lr) * D_MODEL + d0];
        float x0[8], x1[8];
        *(float4*)&x0[0] = *(const float4*)(xr + lg * 8);
        *(float4*)&x0[4] = *(const float4*)(xr + lg * 8 + 4);
        *(float4*)&x1[0] = *(const float4*)(xr + 32 + lg * 8);
        *(float4*)&x1[4] = *(const float4*)(xr + 32 + lg * 8 + 4);
        union { bf16x8 v; uint u[4]; } xh0, xl0, xh1, xl1;
#pragma unroll
        for (int i = 0; i < 4; ++i) {
            tsplit2(x0[2 * i], x0[2 * i + 1], xh0.u[i], xl0.u[i]);
            tsplit2(x1[2 * i], x1[2 * i + 1], xh1.u[i], xl1.u[i]);
        }

#pragma unroll
        for (int m2 = 0; m2 < 4; ++m2) {
            const int row = m2 * 16 + lr;
            bf16x8 wh0 = *(const bf16x8*)&BsH[row][c0s];
            bf16x8 wh1 = *(const bf16x8*)&BsH[row][c1s];
            bf16x8 wl0 = *(const bf16x8*)&BsL[row][c0s];
            bf16x8 wl1 = *(const bf16x8*)&BsL[row][c1s];
            f32x4 a = acc[m2];
            if (which < 2) {   // C^T = Wt * X^T
                a = __builtin_amdgcn_mfma_f32_16x16x32_bf16(wh0, xh0.v, a, 0, 0, 0);
                a = __builtin_amdgcn_mfma_f32_16x16x32_bf16(wh1, xh1.v, a, 0, 0, 0);
                a = __builtin_amdgcn_mfma_f32_16x16x32_bf16(wh0, xl0.v, a, 0, 0, 0);
                a = __builtin_amdgcn_mfma_f32_16x16x32_bf16(wh1, xl1.v, a, 0, 0, 0);
                a = __builtin_amdgcn_mfma_f32_16x16x32_bf16(wl0, xh0.v, a, 0, 0, 0);
                a = __builtin_amdgcn_mfma_f32_16x16x32_bf16(wl1, xh1.v, a, 0, 0, 0);
            } else {           // C = X * Wt^T
                a = __builtin_amdgcn_mfma_f32_16x16x32_bf16(xh0.v, wh0, a, 0, 0, 0);
                a = __builtin_amdgcn_mfma_f32_16x16x32_bf16(xh1.v, wh1, a, 0, 0, 0);
                a = __builtin_amdgcn_mfma_f32_16x16x32_bf16(xl0.v, wh0, a, 0, 0, 0);
                a = __builtin_amdgcn_mfma_f32_16x16x32_bf16(xl1.v, wh1, a, 0, 0, 0);
                a = __builtin_amdgcn_mfma_f32_16x16x32_bf16(xh0.v, wl0, a, 0, 0, 0);
                a = __builtin_amdgcn_mfma_f32_16x16x32_bf16(xh1.v, wl1, a, 0, 0, 0);
            }
            acc[m2] = a;
        }
    }

    if (which < 2) {
        ushort* OH = (ushort*)((char*)ws + (which == 0 ? QHI_B : KHI_B)) + (size_t)bh * T_SEQ * DK;
        ushort* OL = (ushort*)((char*)ws + (which == 0 ? QLO_B : KLO_B)) + (size_t)bh * T_SEQ * DK;
        const float scl = (which == 0) ? QSCALE : 1.0f;
#pragma unroll
        for (int m2 = 0; m2 < 4; ++m2) {
            uint h0, l0, h1, l1;
            tsplit2(acc[m2][0] * scl, acc[m2][1] * scl, h0, l0);
            tsplit2(acc[m2][2] * scl, acc[m2][3] * scl, h1, l1);
            const size_t addr = (size_t)(t0 + w * 16 + lr) * DK + m2 * 16 + lg * 4;
            *(uint2*)&OH[addr] = make_uint2(h0, h1);
            *(uint2*)&OL[addr] = make_uint2(l0, l1);
        }
    } else {
        ushort* OH = (ushort*)((char*)ws + VTHI_B) + (size_t)bh * DK * T_SEQ;
        ushort* OL = (ushort*)((char*)ws + VTLO_B) + (size_t)bh * DK * T_SEQ;
#pragma unroll
        for (int n2 = 0; n2 < 4; ++n2) {
            uint h0, l0, h1, l1;
            tsplit2(acc[n2][0], acc[n2][1], h0, l0);
            tsplit2(acc[n2][2], acc[n2][3], h1, l1);
            const size_t addr = (size_t)(n2 * 16 + lr) * T_SEQ + t0 + w * 16 + lg * 4;
            *(uint2*)&OH[addr] = make_uint2(h0, h1);
            *(uint2*)&OL[addr] = make_uint2(l0, l1);
        }
    }
}

// ---------------------------------------------------------------------------
// Kernel 2: flash attention, MFMA, base-2 softmax, split-K (NCH chunks).
// grid (T/64, BH, NCH), block 256.  K/V/P tiles in XOR-swizzled LDS
// (granule ^= row&7, stride 64 shorts).  Q frags hoisted from global planes.
// ---------------------------------------------------------------------------
__global__ __launch_bounds__(256, 3) void attn_fwd(
    const int* __restrict__ ls_ptr, float* __restrict__ ws)
{
    const int bh = blockIdx.y, b = bh >> 3, h = bh & 7;
    const int mtype = h >> 1;
    const int row0 = blockIdx.x * 64, rb = row0 >> 6;
    const int chunk = blockIdx.z;
    const int ls = *ls_ptr;

    float* mrow = (float*)((char*)ws + MST_B) + ((size_t)chunk * BH + bh) * T_SEQ;
    float* lrow = (float*)((char*)ws + LST_B) + ((size_t)chunk * BH + bh) * T_SEQ;

    int klo = 0, khi = NKB - 1;
    if (mtype == 1) {
        int l2 = row0 - ls; if (l2 < 0) l2 = 0;
        int h2 = row0 + 63 + ls; if (h2 > T_SEQ - 1) h2 = T_SEQ - 1;
        klo = l2 >> 6; khi = h2 >> 6;
    } else if (mtype == 2) {
        klo = rb;
    } else if (mtype == 3) {
        khi = rb;
    }
    const int kb0 = klo > chunk * CHB ? klo : chunk * CHB;
    const int kb1 = khi < chunk * CHB + CHB - 1 ? khi : chunk * CHB + CHB - 1;

    const int tid = threadIdx.x;
    if (kb0 > kb1) {
        if (tid < 64) { mrow[row0 + tid] = -INFINITY; lrow[row0 + tid] = 0.f; }
        return;
    }

    const ushort* Qh_g = (const ushort*)((char*)ws + QHI_B) + (size_t)bh * T_SEQ * DK;
    const ushort* Ql_g = (const ushort*)((char*)ws + QLO_B) + (size_t)bh * T_SEQ * DK;
    const ushort* Kh_g = (const ushort*)((char*)ws + KHI_B) + (size_t)bh * T_SEQ * DK;
    const ushort* Kl_g = (const ushort*)((char*)ws + KLO_B) + (size_t)bh * T_SEQ * DK;
    const ushort* Vh_g = (const ushort*)((char*)ws + VTHI_B) + (size_t)bh * DK * T_SEQ;
    const ushort* Vl_g = (const ushort*)((char*)ws + VTLO_B) + (size_t)bh * DK * T_SEQ;
    float* attP = (float*)((char*)ws + ATTP_B) + (size_t)chunk * CHUNK_F;

    __shared__ ushort KhS[64][64], KlS[64][64];
    __shared__ ushort VhS[64][64], VlS[64][64];
    __shared__ ushort PhS[64][64], PlS[64][64];

    const int lane = tid & 63, w = tid >> 6;
    const int lr = lane & 15, lg = lane >> 4;
    const int sg = tid & 7, srow = tid >> 3;
    const int swz0 = (sg ^ (srow & 7)) * 8;
    const int c0s = (lg ^ (lr & 7)) * 8, c1s = c0s ^ 32;

    // Q fragments (loop-invariant, from global)
    const ushort* qh = Qh_g + (size_t)(row0 + w * 16 + lr) * DK;
    const ushort* ql = Ql_g + (size_t)(row0 + w * 16 + lr) * DK;
    const bf16x8 bqh0 = *(const bf16x8*)(qh + lg * 8);
    const bf16x8 bqh1 = *(const bf16x8*)(qh + 32 + lg * 8);
    const bf16x8 bql0 = *(const bf16x8*)(ql + lg * 8);
    const bf16x8 bql1 = *(const bf16x8*)(ql + 32 + lg * 8);

    float m_i = -INFINITY, l_i = 0.f;
    f32x4 oacc[4];
#pragma unroll
    for (int i = 0; i < 4; ++i) oacc[i] = (f32x4){0.f, 0.f, 0.f, 0.f};

    uint4 kr0, kr1, kr2, kr3, vr0, vr1, vr2, vr3;
    kr0 = *(const uint4*)&Kh_g[(size_t)(kb0 * 64 + srow) * DK + sg * 8];
    kr1 = *(const uint4*)&Kh_g[(size_t)(kb0 * 64 + srow + 32) * DK + sg * 8];
    kr2 = *(const uint4*)&Kl_g[(size_t)(kb0 * 64 + srow) * DK + sg * 8];
    kr3 = *(const uint4*)&Kl_g[(size_t)(kb0 * 64 + srow + 32) * DK + sg * 8];
    vr0 = *(const uint4*)&Vh_g[(size_t)srow * T_SEQ + kb0 * 64 + sg * 8];
    vr1 = *(const uint4*)&Vh_g[(size_t)(srow + 32) * T_SEQ + kb0 * 64 + sg * 8];
    vr2 = *(const uint4*)&Vl_g[(size_t)srow * T_SEQ + kb0 * 64 + sg * 8];
    vr3 = *(const uint4*)&Vl_g[(size_t)(srow + 32) * T_SEQ + kb0 * 64 + sg * 8];

    for (int kb = kb0; kb <= kb1; ++kb) {
        __syncthreads();
        *(uint4*)&KhS[srow][swz0] = kr0; *(uint4*)&KhS[srow + 32][swz0] = kr1;
        *(uint4*)&KlS[srow][swz0] = kr2; *(uint4*)&KlS[srow + 32][swz0] = kr3;
        *(uint4*)&VhS[srow][swz0] = vr0; *(uint4*)&VhS[srow + 32][swz0] = vr1;
        *(uint4*)&VlS[srow][swz0] = vr2; *(uint4*)&VlS[srow + 32][swz0] = vr3;
        if (kb < kb1) {
            const int kn = kb + 1;
            kr0 = *(const uint4*)&Kh_g[(size_t)(kn * 64 + srow) * DK + sg * 8];
            kr1 = *(const uint4*)&Kh_g[(size_t)(kn * 64 + srow + 32) * DK + sg * 8];
            kr2 = *(const uint4*)&Kl_g[(size_t)(kn * 64 + srow) * DK + sg * 8];
            kr3 = *(const uint4*)&Kl_g[(size_t)(kn * 64 + srow + 32) * DK + sg * 8];
            vr0 = *(const uint4*)&Vh_g[(size_t)srow * T_SEQ + kn * 64 + sg * 8];
            vr1 = *(const uint4*)&Vh_g[(size_t)(srow + 32) * T_SEQ + kn * 64 + sg * 8];
            vr2 = *(const uint4*)&Vl_g[(size_t)srow * T_SEQ + kn * 64 + sg * 8];
            vr3 = *(const uint4*)&Vl_g[(size_t)(srow + 32) * T_SEQ + kn * 64 + sg * 8];
        }
        __syncthreads();

        // ---- QK: S^T[s][t] = K . Q^T ----
        f32x4 sacc[4];
#pragma unroll
        for (int m = 0; m < 4; ++m) {
            const int row = m * 16 + lr;
            bf16x8 ah0 = *(const bf16x8*)&KhS[row][c0s];
            bf16x8 ah1 = *(const bf16x8*)&KhS[row][c1s];
            bf16x8 al0 = *(const bf16x8*)&KlS[row][c0s];
            bf16x8 al1 = *(const bf16x8*)&KlS[row][c1s];
            f32x4 a = (f32x4){0.f, 0.f, 0.f, 0.f};
            a = __builtin_amdgcn_mfma_f32_16x16x32_bf16(ah0, bqh0, a, 0, 0, 0);
            a = __builtin_amdgcn_mfma_f32_16x16x32_bf16(ah1, bqh1, a, 0, 0, 0);
            a = __builtin_amdgcn_mfma_f32_16x16x32_bf16(ah0, bql0, a, 0, 0, 0);
            a = __builtin_amdgcn_mfma_f32_16x16x32_bf16(ah1, bql1, a, 0, 0, 0);
            a = __builtin_amdgcn_mfma_f32_16x16x32_bf16(al0, bqh0, a, 0, 0, 0);
            a = __builtin_amdgcn_mfma_f32_16x16x32_bf16(al1, bqh1, a, 0, 0, 0);
            sacc[m] = a;
        }

        // ---- mask + online softmax (base 2; t = lane&15) ----
        const int t_glob = row0 + w * 16 + lr;
        const bool needmask = (mtype == 1) || ((mtype >= 2) && (kb == rb));
        float p[4][4];
        float vmax = -INFINITY;
#pragma unroll
        for (int m = 0; m < 4; ++m)
#pragma unroll
            for (int r = 0; r < 4; ++r) {
                float x = sacc[m][r];
                if (needmask) {
                    int s_glob = kb * 64 + m * 16 + lg * 4 + r;
                    bool keep;
                    if (mtype == 1) keep = (t_glob - s_glob <= ls) && (s_glob - t_glob <= ls);
                    else if (mtype == 2) keep = (s_glob >= t_glob);
                    else keep = (s_glob <= t_glob);
                    if (!keep) x = -INFINITY;
                }
                p[m][r] = x;
                vmax = fmaxf(vmax, x);
            }
        vmax = fmaxf(vmax, __shfl_xor(vmax, 16, 64));
        vmax = fmaxf(vmax, __shfl_xor(vmax, 32, 64));
        const float mn = fmaxf(m_i, vmax);
        float factor = 1.f, psum = 0.f;
        if (mn == -INFINITY) {
#pragma unroll
            for (int m = 0; m < 4; ++m)
#pragma unroll
                for (int r = 0; r < 4; ++r) p[m][r] = 0.f;
        } else {
            factor = exp2f(m_i - mn);
            m_i = mn;
#pragma unroll
            for (int m = 0; m < 4; ++m)
#pragma unroll
                for (int r = 0; r < 4; ++r) {
                    p[m][r] = exp2f(p[m][r] - mn);
                    psum += p[m][r];
                }
        }
        psum += __shfl_xor(psum, 16, 64);
        psum += __shfl_xor(psum, 32, 64);
        l_i = l_i * factor + psum;

        // ---- store P (t-major, swizzled) ----
#pragma unroll
        for (int m = 0; m < 4; ++m) {
            uint ph01, pl01, ph23, pl23;
            tsplit2(p[m][0], p[m][1], ph01, pl01);
            tsplit2(p[m][2], p[m][3], ph23, pl23);
            const int pg = (((m * 2 + (lg >> 1)) ^ (lr & 7)) * 8) + (lg & 1) * 4;
            *(uint2*)&PhS[w * 16 + lr][pg] = make_uint2(ph01, ph23);
            *(uint2*)&PlS[w * 16 + lr][pg] = make_uint2(pl01, pl23);
        }

        // ---- rescale O ----
        float fr[4];
#pragma unroll
        for (int r = 0; r < 4; ++r) fr[r] = __shfl(factor, lg * 4 + r, 64);
#pragma unroll
        for (int n2 = 0; n2 < 4; ++n2)
#pragma unroll
            for (int r = 0; r < 4; ++r) oacc[n2][r] *= fr[r];

        // ---- PV: O[t][dk] += P V ----
        const bf16x8 aph0 = *(const bf16x8*)&PhS[w * 16 + lr][c0s];
        const bf16x8 aph1 = *(const bf16x8*)&PhS[w * 16 + lr][c1s];
        const bf16x8 apl0 = *(const bf16x8*)&PlS[w * 16 + lr][c0s];
        const bf16x8 apl1 = *(const bf16x8*)&PlS[w * 16 + lr][c1s];
#pragma unroll
        for (int n2 = 0; n2 < 4; ++n2) {
            const int row = n2 * 16 + lr;
            bf16x8 bh0 = *(const bf16x8*)&VhS[row][c0s];
            bf16x8 bh1 = *(const bf16x8*)&VhS[row][c1s];
            bf16x8 bl0 = *(const bf16x8*)&VlS[row][c0s];
            bf16x8 bl1 = *(const bf16x8*)&VlS[row][c1s];
            f32x4 a = oacc[n2];
            a = __builtin_amdgcn_mfma_f32_16x16x32_bf16(aph0, bh0, a, 0, 0, 0);
            a = __builtin_amdgcn_mfma_f32_16x16x32_bf16(aph1, bh1, a, 0, 0, 0);
            a = __builtin_amdgcn_mfma_f32_16x16x32_bf16(aph0, bl0, a, 0, 0, 0);
            a = __builtin_amdgcn_mfma_f32_16x16x32_bf16(aph1, bl1, a, 0, 0, 0);
            a = __builtin_amdgcn_mfma_f32_16x16x32_bf16(apl0, bh0, a, 0, 0, 0);
            a = __builtin_amdgcn_mfma_f32_16x16x32_bf16(apl1, bh1, a, 0, 0, 0);
            oacc[n2] = a;
        }
    }

#pragma unroll
    for (int n2 = 0; n2 < 4; ++n2)
#pragma unroll
        for (int r = 0; r < 4; ++r) {
            int t = row0 + w * 16 + lg * 4 + r;
            attP[((size_t)b * T_SEQ + t) * HK + h * DK + n2 * 16 + lr] = oacc[n2][r];
        }
    if (lg == 0) {
        mrow[row0 + w * 16 + lr] = m_i;
        lrow[row0 + w * 16 + lr] = l_i;
    }
}

// ---------------------------------------------------------------------------
// Kernel 3: per-(b,h) reduce of (m,l) over chunks -> scale (base-2 domain).
// ---------------------------------------------------------------------------
__global__ __launch_bounds__(256) void softmax_stats(float* __restrict__ ws)
{
    const int bh = blockIdx.x;
    float* mbase = (float*)((char*)ws + MST_B);
    float* lbase = (float*)((char*)ws + LST_B);
    float* sbase = (float*)((char*)ws + SST_B);

    __shared__ float red[256];
    const int tid = threadIdx.x;
    const int n = NCH * T_SEQ;

    float mymax = -INFINITY;
    for (int i = tid; i < n; i += 256) {
        int c = i >> 11, t = i & 2047;
        mymax = fmaxf(mymax, mbase[((size_t)c * BH + bh) * T_SEQ + t]);
    }
    red[tid] = mymax; __syncthreads();
    for (int s = 128; s > 0; s >>= 1) {
        if (tid < s) red[tid] = fmaxf(red[tid], red[tid + s]);
        __syncthreads();
    }
    const float M = red[0]; __syncthreads();

    float mysum = 0.f;
    for (int i = tid; i < n; i += 256) {
        int c = i >> 11, t = i & 2047;
        size_t idx = ((size_t)c * BH + bh) * T_SEQ + t;
        mysum += lbase[idx] * exp2f(mbase[idx] - M);
    }
    red[tid] = mysum; __syncthreads();
    for (int s = 128; s > 0; s >>= 1) {
        if (tid < s) red[tid] += red[tid + s];
        __syncthreads();
    }
    const float Z = red[0];

    for (int i = tid; i < n; i += 256) {
        int c = i >> 11, t = i & 2047;
        size_t idx = ((size_t)c * BH + bh) * T_SEQ + t;
        sbase[idx] = exp2f(mbase[idx] - M) / Z;
    }
}

// ---------------------------------------------------------------------------
// Kernel 4: attS(bf16 hi/lo) = sum_c attP[c] * scale[c].  grid 2048 x 256.
// ---------------------------------------------------------------------------
__global__ __launch_bounds__(256) void reduce_split(float* __restrict__ ws)
{
    const size_t flat = ((size_t)blockIdx.x * 256 + threadIdx.x) * 4;
    const float* attP = (const float*)((char*)ws + ATTP_B);
    const float* sc = (const float*)((char*)ws + SST_B);
    ushort* SH = (ushort*)((char*)ws + ATTSHI_B);
    ushort* SL = (ushort*)((char*)ws + ATTSLO_B);

    const int hk = (int)(flat & (HK - 1));
    const size_t bt = flat / HK;
    const int b = (int)(bt >> 11), t = (int)(bt & 2047);
    const int h = hk >> 6;

    float4 acc = make_float4(0.f, 0.f, 0.f, 0.f);
    for (int c = 0; c < NCH; ++c) {
        float4 a = *(const float4*)&attP[(size_t)c * CHUNK_F + flat];
        float s = sc[((size_t)c * BH + b * NH + h) * T_SEQ + t];
        acc.x = fmaf(a.x, s, acc.x); acc.y = fmaf(a.y, s, acc.y);
        acc.z = fmaf(a.z, s, acc.z); acc.w = fmaf(a.w, s, acc.w);
    }
    uint h0, l0, h1, l1;
    tsplit2(acc.x, acc.y, h0, l0);
    tsplit2(acc.z, acc.w, h1, l1);
    *(uint2*)&SH[flat] = make_uint2(h0, h1);
    *(uint2*)&SL[flat] = make_uint2(l0, l1);
}

// ---------------------------------------------------------------------------
// Kernel 5: out = attS . Wo  via 3-term bf16-split MFMA.
// grid (D/64, B*T/64), block 256.
// ---------------------------------------------------------------------------
__global__ __launch_bounds__(256) void out_proj_mfma(
    float* __restrict__ ws, float* __restrict__ out)
{
    const int d0 = blockIdx.x * 64;
    const int r0 = blockIdx.y * 64;
    const ushort* AH = (const ushort*)((char*)ws + ATTSHI_B);
    const ushort* AL = (const ushort*)((char*)ws + ATTSLO_B);
    const ushort* WoH = (const ushort*)((char*)ws + WOTHI_B);
    const ushort* WoL = (const ushort*)((char*)ws + WOTLO_B);

    __shared__ ushort BsH[64][64], BsL[64][64];

    const int tid = threadIdx.x, lane = tid & 63, w = tid >> 6;
    const int lr = lane & 15, lg = lane >> 4;
    const int sg = tid & 7, srow = tid >> 3;
    const int swz0 = (sg ^ (srow & 7)) * 8;
    const int c0s = (lg ^ (lr & 7)) * 8, c1s = c0s ^ 32;

    f32x4 acc[4];
#pragma unroll
    for (int i = 0; i < 4; ++i) acc[i] = (f32x4){0.f, 0.f, 0.f, 0.f};

    for (int k0 = 0; k0 < HK; k0 += 64) {
        __syncthreads();
        *(uint4*)&BsH[srow][swz0]      = *(const uint4*)&WoH[(size_t)(d0 + srow) * HK + k0 + sg * 8];
        *(uint4*)&BsH[srow + 32][swz0] = *(const uint4*)&WoH[(size_t)(d0 + srow + 32) * HK + k0 + sg * 8];
        *(uint4*)&BsL[srow][swz0]      = *(const uint4*)&WoL[(size_t)(d0 + srow) * HK + k0 + sg * 8];
        *(uint4*)&BsL[srow + 32][swz0] = *(const uint4*)&WoL[(size_t)(d0 + srow + 32) * HK + k0 + sg * 8];
        __syncthreads();

        const ushort* ar = AH + (size_t)(r0 + w * 16 + lr) * HK + k0;
        const ushort* al = AL + (size_t)(r0 + w * 16 + lr) * HK + k0;
        bf16x8 ah0 = *(const bf16x8*)(ar + lg * 8);
        bf16x8 ah1 = *(const bf16x8*)(ar + 32 + lg * 8);
        bf16x8 al0 = *(const bf16x8*)(al + lg * 8);
        bf16x8 al1 = *(const bf16x8*)(al + 32 + lg * 8);

#pragma unroll
        for (int n2 = 0; n2 < 4; ++n2) {
            const int row = n2 * 16 + lr;
            bf16x8 wh0 = *(const bf16x8*)&BsH[row][c0s];
            bf16x8 wh1 = *(const bf16x8*)&BsH[row][c1s];
            bf16x8 wl0 = *(const bf16x8*)&BsL[row][c0s];
            bf16x8 wl1 = *(const bf16x8*)&BsL[row][c1s];
            f32x4 a = acc[n2];
            a = __builtin_amdgcn_mfma_f32_16x16x32_bf16(ah0, wh0, a, 0, 0, 0);
            a = __builtin_amdgcn_mfma_f32_16x16x32_bf16(ah1, wh1, a, 0, 0, 0);
            a = __builtin_amdgcn_mfma_f32_16x16x32_bf16(ah0, wl0, a, 0, 0, 0);
            a = __builtin_amdgcn_mfma_f32_16x16x32_bf16(ah1, wl1, a, 0, 0, 0);
            a = __builtin_amdgcn_mfma_f32_16x16x32_bf16(al0, wh0, a, 0, 0, 0);
            a = __builtin_amdgcn_mfma_f32_16x16x32_bf16(al1, wh1, a, 0, 0, 0);
            acc[n2] = a;
        }
    }

#pragma unroll
    for (int n2 = 0; n2 < 4; ++n2)
#pragma unroll
        for (int i = 0; i < 4; ++i)
            out[(size_t)(r0 + w * 16 + lg * 4 + i) * D_MODEL + d0 + n2 * 16 + lr] = acc[n2][i];
}

// ---------------------------------------------------------------------------
extern "C" void kernel_launch(void* const* d_in, const int* in_sizes, int n_in,
                              void* d_out, int out_size, void* d_ws, size_t ws_size,
                              hipStream_t stream)
{
    const float* query = (const float*)d_in[0];
    const float* value = (const float*)d_in[1];
    const float* Wq = (const float*)d_in[2];
    const float* Wk = (const float*)d_in[3];
    const float* Wv = (const float*)d_in[4];
    const float* Wo = (const float*)d_in[5];
    const int* ls = (const int*)d_in[6];
    float* out = (float*)d_out;
    float* ws = (float*)d_ws;

    split_w<<<dim3(2048), 256, 0, stream>>>(Wq, Wk, Wv, Wo, ws);

    proj_mfma<<<dim3(T_SEQ / 64, BH, 3), 256, 0, stream>>>(query, value, ws);

    attn_fwd<<<dim3(T_SEQ / 64, BH, NCH), 256, 0, stream>>>(ls, ws);

    softmax_stats<<<dim3(BH), 256, 0, stream>>>(ws);

    reduce_split<<<dim3(2 * T_SEQ * HK / 1024), 256, 0, stream>>>(ws);

    out_proj_mfma<<<dim3(D_MODEL / 64, 2 * T_SEQ / 64), 256, 0, stream>>>(ws, out);
}